// Round 7
// baseline (493.763 us; speedup 1.0000x reference)
//
#include <hip/hip_runtime.h>
#include <hip/hip_bf16.h>

#define BB 16
#define SS 512
#define DM 256
#define NH 8

// workspace layout in float units
#define OFF_QB    0         // bf16 Q  [b,s,c]  2097152 elem
#define OFF_KB    1048576   // bf16 K  [b,s,c]
#define OFF_VT    2097152   // bf16 V^T [b,c,s]
#define OFF_VP2   3145728   // f32 [b,s,32]
#define OFF_CTXB  3407872   // bf16 ctx [b,s,256]
#define OFF_CTX2B 4456448   // bf16 ctx2 [b,s,32]
#define OFF_G     4587520   // bf16 g [b,q,k]
#define OFF_FLAG  6684672   // 1 uint
#define OFF_PM    6684674   // packed mask bits, 524288 u64 = 4 MB
#define OFF_PWS   7733250   // bf16 P (unnormalized e) [b,h,q,k] 33.5M elem = 67 MB
// total ws = 24510466 floats ~= 98 MB (harness ws pool is 512 MiB per fill size)

#define SCALE 0.17677669529663687f
// SCALE * log2(e): exp(SCALE*x) == exp2(KE2*x)
#define KE2 0.2550348623f

typedef __attribute__((ext_vector_type(8))) short bfrag8;  // 8 bf16 (4 VGPR)
typedef __attribute__((ext_vector_type(4))) float facc4;   // MFMA accumulator

// ---------------------------------------------------------------------------
// K0: OR-reduce first 64K words of the mask into *acc (acc pre-zeroed).
__global__ void mask_or_kernel(const unsigned int* __restrict__ w,
                               unsigned int* __restrict__ acc) {
  __shared__ unsigned int sh[256];
  unsigned int a = 0;
  int base = blockIdx.x * 1024;
  for (int i = threadIdx.x; i < 1024; i += 256) a |= w[base + i];
  sh[threadIdx.x] = a;
  __syncthreads();
  for (int s = 128; s > 0; s >>= 1) {
    if (threadIdx.x < s) sh[threadIdx.x] |= sh[threadIdx.x + s];
    __syncthreads();
  }
  if (threadIdx.x == 0) atomicOr(acc, sh[0]);
}

// ---------------------------------------------------------------------------
// K0b: pack mask into bits (1 bit/elem, 4 MB). __ballot of 64 lanes IS the word.
__global__ __launch_bounds__(256) void mask_pack_kernel(
    const void* __restrict__ mask, unsigned long long* __restrict__ pm,
    const unsigned int* __restrict__ orv) {
  const unsigned int rawor = *orv;
  const int flagv = (rawor <= 1u) ? 0 : ((rawor == 0x3F800000u) ? 2 : 1);
  const int lane = threadIdx.x & 63;
  const int wv = threadIdx.x >> 6;
  const int w0 = (blockIdx.x * 4 + wv) * 32;
  const unsigned char* mb = (const unsigned char*)mask;
  const int* mi = (const int*)mask;
  const float* mf = (const float*)mask;
  unsigned long long myw = 0;
#pragma unroll 4
  for (int i = 0; i < 32; i++) {
    long long idx = (long long)(w0 + i) * 64 + lane;
    bool m;
    if (flagv == 1) m = (mb[idx] != 0);
    else if (flagv == 0) m = (mi[idx] != 0);
    else m = (mf[idx] != 0.f);
    unsigned long long bits = __ballot(m);
    if (lane == i) myw = bits;
  }
  if (lane < 32) pm[w0 + lane] = myw;
}

// ---------------------------------------------------------------------------
// K1: MFMA GEMM for Q/K/V projections (unchanged).
__global__ __launch_bounds__(256) void gemm_qkv_kernel(
    const float* __restrict__ inQ, const float* __restrict__ inK,
    const float* __restrict__ inV,
    const float* __restrict__ Wq, const float* __restrict__ Wk,
    const float* __restrict__ Wv,
    __hip_bfloat16* __restrict__ Qb, __hip_bfloat16* __restrict__ Kb,
    __hip_bfloat16* __restrict__ Vt) {
  __shared__ __align__(16) __hip_bfloat16 As[64][40];
  __shared__ __align__(16) __hip_bfloat16 Bs[64][40];
  const int tid = threadIdx.x;
  const int bid = blockIdx.x;
  const int matid = bid >> 9;
  const int mblk = (bid & 511) >> 2;
  const int nblk = bid & 3;
  const int m0 = mblk * 64;
  const int n0 = nblk * 64;
  const float* X = (matid == 0) ? inQ : (matid == 1) ? inK : inV;
  const float* W = (matid == 0) ? Wq : (matid == 1) ? Wk : Wv;

  const int lane = tid & 63;
  const int w = tid >> 6;
  const int wm = w & 1, wn = w >> 1;
  const int cl = lane & 15, quad = lane >> 4;
  const int arow = tid >> 2, ak8 = (tid & 3) * 8;
  const int bn = tid & 63, bk8 = (tid >> 6) * 8;

  facc4 acc[2][2];
#pragma unroll
  for (int t = 0; t < 2; t++)
#pragma unroll
    for (int u = 0; u < 2; u++) acc[t][u] = (facc4){0.f, 0.f, 0.f, 0.f};

#pragma unroll 1
  for (int kc = 0; kc < 8; kc++) {
    float4 x0 = *(const float4*)&X[(m0 + arow) * 256 + kc * 32 + ak8];
    float4 x1 = *(const float4*)&X[(m0 + arow) * 256 + kc * 32 + ak8 + 4];
    float wv[8];
#pragma unroll
    for (int j = 0; j < 8; j++) wv[j] = W[(kc * 32 + bk8 + j) * 256 + n0 + bn];
    __syncthreads();
    {
      __hip_bfloat16 ta[8];
      ta[0] = __float2bfloat16(x0.x); ta[1] = __float2bfloat16(x0.y);
      ta[2] = __float2bfloat16(x0.z); ta[3] = __float2bfloat16(x0.w);
      ta[4] = __float2bfloat16(x1.x); ta[5] = __float2bfloat16(x1.y);
      ta[6] = __float2bfloat16(x1.z); ta[7] = __float2bfloat16(x1.w);
      *(uint4*)&As[arow][ak8] = *(uint4*)ta;
      __hip_bfloat16 tb[8];
#pragma unroll
      for (int j = 0; j < 8; j++) tb[j] = __float2bfloat16(wv[j]);
      *(uint4*)&Bs[bn][bk8] = *(uint4*)tb;
    }
    __syncthreads();
    bfrag8 aA[2], bB[2];
#pragma unroll
    for (int t = 0; t < 2; t++)
      aA[t] = *(const bfrag8*)&As[wm * 32 + t * 16 + cl][quad * 8];
#pragma unroll
    for (int u = 0; u < 2; u++)
      bB[u] = *(const bfrag8*)&Bs[wn * 32 + u * 16 + cl][quad * 8];
#pragma unroll
    for (int t = 0; t < 2; t++)
#pragma unroll
      for (int u = 0; u < 2; u++)
        acc[t][u] =
            __builtin_amdgcn_mfma_f32_16x16x32_bf16(aA[t], bB[u], acc[t][u], 0, 0, 0);
  }

  if (matid < 2) {
    __hip_bfloat16* Y = (matid == 0) ? Qb : Kb;
#pragma unroll
    for (int t = 0; t < 2; t++)
#pragma unroll
      for (int u = 0; u < 2; u++)
#pragma unroll
        for (int reg = 0; reg < 4; reg++)
          Y[(m0 + wm * 32 + t * 16 + quad * 4 + reg) * 256 + n0 + wn * 32 +
            u * 16 + cl] = __float2bfloat16(acc[t][u][reg]);
  } else {
#pragma unroll
    for (int t = 0; t < 2; t++)
#pragma unroll
      for (int u = 0; u < 2; u++) {
        int c = n0 + wn * 32 + u * 16 + cl;
        int mg = m0 + wm * 32 + t * 16 + quad * 4;
        int b = mg >> 9, s = mg & 511;
        __hip_bfloat16 pk[4];
#pragma unroll
        for (int reg = 0; reg < 4; reg++)
          pk[reg] = __float2bfloat16(acc[t][u][reg]);
        *(ushort4*)&Vt[(((b << 8) + c) << 9) + s] = *(ushort4*)pk;
      }
  }
}

// ---------------------------------------------------------------------------
// K1b: Vp2 = inV @ Wv2 (unchanged).
__global__ __launch_bounds__(256) void vp2_kernel(
    const float* __restrict__ inV, const float* __restrict__ Wv2,
    float* __restrict__ Vp2) {
  __shared__ __align__(16) float xs[16][260];
  const int t = threadIdx.x;
  const int r0 = blockIdx.x * 16;
  for (int e = t; e < 16 * 256; e += 256) {
    int r = e >> 8, i = e & 255;
    xs[r][i] = inV[(r0 + r) * 256 + i];
  }
  __syncthreads();
  const int c2 = t & 31, rr = t >> 5;
  float a0 = 0.f, a1 = 0.f;
  for (int i = 0; i < 256; i += 4) {
    float w0 = Wv2[i * 32 + c2], w1 = Wv2[(i + 1) * 32 + c2];
    float w2 = Wv2[(i + 2) * 32 + c2], w3 = Wv2[(i + 3) * 32 + c2];
    float4 xa = *(const float4*)&xs[rr][i];
    float4 xb = *(const float4*)&xs[rr + 8][i];
    a0 += xa.x * w0 + xa.y * w1 + xa.z * w2 + xa.w * w3;
    a1 += xb.x * w0 + xb.y * w1 + xb.z * w2 + xb.w * w3;
  }
  Vp2[(r0 + rr) * 32 + c2] = a0;
  Vp2[(r0 + rr + 8) * 32 + c2] = a1;
}

// ---------------------------------------------------------------------------
// K2: fused attention — R7: occupancy fix at CONSTANT work (R3 lesson).
// Same block decomposition as R2/R6 (16 q-rows, all 8 heads, grid 512), but
// the P (unnormalized e) buffer moves LDS -> global Pws [b,h,q,k] bf16.
// LDS drops 133 KB -> <1 KB => occupancy 1 block/CU -> 2-4 blocks/CU.
// All P reads (gate: 128 KB, AV: 16 KB) were written by this same block
// => L2-resident read-back; __syncthreads drains vmcnt so writes are at L2.
__global__ __launch_bounds__(512, 4) void attn_kernel(
    const __hip_bfloat16* __restrict__ Qb, const __hip_bfloat16* __restrict__ Kb,
    const __hip_bfloat16* __restrict__ Vt,
    const unsigned long long* __restrict__ pm,
    const float* __restrict__ matrix,
    const float* __restrict__ fulng, const float* __restrict__ fulnb,
    const float* __restrict__ fuw1, const float* __restrict__ fub1,
    const float* __restrict__ fuw2, const float* __restrict__ fub2,
    __hip_bfloat16* __restrict__ ctxb, __hip_bfloat16* __restrict__ gws,
    __hip_bfloat16* __restrict__ Pws) {
  __shared__ float inv_s[NH][16];
  __shared__ float gp[80];  // GW1[0..53], S1[54..59], C1[60..65], w2[66..71], b2[72]

  const int tid = threadIdx.x;
  const int lane = tid & 63;
  const int h = tid >> 6;
  const int cl = lane & 15, quad = lane >> 4;
  // XCD swizzle: 2 batches per XCD
  const int b = ((blockIdx.x & 7) << 1) | (blockIdx.x >> 8);
  const int q0 = ((blockIdx.x >> 3) & 31) * 16;

  // gate-param precompute (visible after the main __syncthreads below)
  if (tid < 6) {
    const int j = tid;
    float s1 = 0.f, c1 = fub1[j];
#pragma unroll
    for (int t = 0; t < 9; t++) {
      float w = fuw1[t * 6 + j];
      float gw = fulng[t] * w;
      gp[t * 6 + j] = gw;
      s1 += gw;
      c1 += fulnb[t] * w;
    }
    gp[54 + j] = s1;
    gp[60 + j] = c1;
    gp[66 + j] = fuw2[j];
    if (j == 0) gp[72] = fub2[0];
  }

  // packed-mask base for this (b, h, q0); row r word w at pmb[r*8 + w]
  const unsigned long long* pmb = pm + (((b * NH + h) << 9) + q0) * 8;
  // P plane for this block's own head, rows q0..q0+15
  __hip_bfloat16* PbO = Pws + ((long long)((b * NH + h) << 9) + q0) * 512;

  const bfrag8 aQ =
      *(const bfrag8*)&Qb[(((b << 9) + q0 + cl) << 8) + h * 32 + quad * 8];
  const __hip_bfloat16* KbB = &Kb[((b << 9) << 8) + h * 32 + quad * 8];
  const __hip_bfloat16* VtB = &Vt[(((b << 8) + h * 32) << 9)];

  // ---- single pass: scores -> e -> global P, accumulate row sums ----
  float l[4] = {0.f, 0.f, 0.f, 0.f};
#pragma unroll 4
  for (int w8 = 0; w8 < 8; w8++) {
    unsigned long long mw[4];
#pragma unroll
    for (int r = 0; r < 4; r++)
      mw[r] = pmb[(quad * 4 + r) * 8 + w8] >> cl;  // bit n4*16: col n4*16+cl
#pragma unroll
    for (int n4 = 0; n4 < 4; n4++) {
      const int nt = w8 * 4 + n4;
      bfrag8 bK = *(const bfrag8*)&KbB[(nt * 16 + cl) << 8];
      facc4 cc = {0.f, 0.f, 0.f, 0.f};
      cc = __builtin_amdgcn_mfma_f32_16x16x32_bf16(aQ, bK, cc, 0, 0, 0);
#pragma unroll
      for (int r = 0; r < 4; r++) {
        float e = ((mw[r] >> (n4 * 16)) & 1ULL) ? 0.f : exp2f(KE2 * cc[r]);
        l[r] += e;
        PbO[(quad * 4 + r) * 512 + nt * 16 + cl] = __float2bfloat16(e);
      }
    }
  }
#pragma unroll
  for (int r = 0; r < 4; r++)
#pragma unroll
    for (int off = 1; off <= 8; off <<= 1) l[r] += __shfl_xor(l[r], off);
  float invl[4];
#pragma unroll
  for (int r = 0; r < 4; r++) invl[r] = 1.f / l[r];
  if (cl == 0) {
#pragma unroll
    for (int r = 0; r < 4; r++) inv_s[h][quad * 4 + r] = invl[r];
  }
  __threadfence_block();
  __syncthreads();  // vmcnt(0) drains P stores to L2; inv_s + gp visible

  // ---- AV: ctx = (sum e*V) * invl; A-frags from own-head P (L2-hot) ----
  facc4 a0 = {0.f, 0.f, 0.f, 0.f}, a1 = {0.f, 0.f, 0.f, 0.f};
#pragma unroll 8
  for (int ks = 0; ks < 16; ks++) {
    bfrag8 aP = *(const bfrag8*)&PbO[cl * 512 + ks * 32 + quad * 8];
    bfrag8 b0 = *(const bfrag8*)&VtB[(cl << 9) + ks * 32 + quad * 8];
    bfrag8 b1 = *(const bfrag8*)&VtB[((16 + cl) << 9) + ks * 32 + quad * 8];
    a0 = __builtin_amdgcn_mfma_f32_16x16x32_bf16(aP, b0, a0, 0, 0, 0);
    a1 = __builtin_amdgcn_mfma_f32_16x16x32_bf16(aP, b1, a1, 0, 0, 0);
  }

  // ---- gate: thread -> (gq, 4 consecutive k), 4 strips of 128 cols ----
  {
    const int gq = tid >> 5;
    const int g32 = (tid & 31) * 4;
#pragma unroll 2
    for (int s = 0; s < 4; s++) {
      const int k4 = s * 128 + g32;
      float4 mrow =
          *(const float4*)&matrix[((b << 9) + q0 + gq) * 512 + k4];
      float p[NH][4];
#pragma unroll
      for (int hh = 0; hh < NH; hh++) {
        const float iv = inv_s[hh][gq];
        ushort4 sv = *(const ushort4*)&Pws[((long long)((b * NH + hh) << 9) +
                                           q0 + gq) * 512 + k4];
        p[hh][0] = __bfloat162float(*(__hip_bfloat16*)&sv.x) * iv;
        p[hh][1] = __bfloat162float(*(__hip_bfloat16*)&sv.y) * iv;
        p[hh][2] = __bfloat162float(*(__hip_bfloat16*)&sv.z) * iv;
        p[hh][3] = __bfloat162float(*(__hip_bfloat16*)&sv.w) * iv;
      }
      const float mcomp[4] = {mrow.x, mrow.y, mrow.z, mrow.w};
      __hip_bfloat16 gout[4];
#pragma unroll
      for (int i = 0; i < 4; i++) {
        float v[9];
        v[0] = mcomp[i];
#pragma unroll
        for (int t = 0; t < NH; t++) v[1 + t] = p[t][i];
        float s1 = 0.f, s2 = 0.f;
#pragma unroll
        for (int t = 0; t < 9; t++) {
          s1 += v[t];
          s2 += v[t] * v[t];
        }
        float mu = s1 * (1.f / 9.f);
        float var = s2 * (1.f / 9.f) - mu * mu;
        float inv = rsqrtf(var + 1e-5f);
        float o = gp[72];
#pragma unroll
        for (int j = 0; j < 6; j++) {
          float d = 0.f;
#pragma unroll
          for (int t = 0; t < 9; t++) d += v[t] * gp[t * 6 + j];
          float z = inv * (d - mu * gp[54 + j]) + gp[60 + j];
          z = fmaxf(z, 0.f);
          o += z * gp[66 + j];
        }
        gout[i] = __float2bfloat16(1.f / (1.f + __expf(-o)));
      }
      *(ushort4*)&gws[((b << 9) + q0 + gq) * 512 + k4] = *(ushort4*)gout;
    }
  }

  // ---- epilogue: scale + write ctx ----
#pragma unroll
  for (int r = 0; r < 4; r++) {
    int row = quad * 4 + r;
    ctxb[((b << 9) + q0 + row) * 256 + h * 32 + cl] =
        __float2bfloat16(a0[r] * invl[r]);
    ctxb[((b << 9) + q0 + row) * 256 + h * 32 + 16 + cl] =
        __float2bfloat16(a1[r] * invl[r]);
  }
}

// ---------------------------------------------------------------------------
// K3: mout[b,j,i] = matrix[b,j,i] * g[b,i,j] (unchanged).
__global__ __launch_bounds__(256) void mout_kernel(
    const float* __restrict__ matrix, const __hip_bfloat16* __restrict__ g,
    float* __restrict__ mout) {
  __shared__ float Gs[64][65];
  const int tid = threadIdx.x;
  const int b = blockIdx.x >> 6;
  const int j0 = ((blockIdx.x >> 3) & 7) * 64;
  const int i0 = (blockIdx.x & 7) * 64;

  {
    int r = tid >> 2, c0 = (tid & 3) * 16;
    const __hip_bfloat16* gpx = g + (((b << 9) + i0 + r) << 9) + j0 + c0;
    ushort us[16];
    *(uint4*)(us) = *(const uint4*)(gpx);
    *(uint4*)(us + 8) = *(const uint4*)(gpx + 8);
#pragma unroll
    for (int k = 0; k < 16; k++) {
      __hip_bfloat16 hv = *(__hip_bfloat16*)&us[k];
      Gs[r][c0 + k] = __bfloat162float(hv);
    }
  }
  __syncthreads();

  {
    int jj = tid >> 2, ic = (tid & 3) * 16;
    const float* mp = matrix + (((b << 9) + j0 + jj) << 9) + i0 + ic;
    float* op = mout + (((b << 9) + j0 + jj) << 9) + i0 + ic;
#pragma unroll
    for (int v4 = 0; v4 < 4; v4++) {
      float4 m = *(const float4*)(mp + v4 * 4);
      float4 o;
      o.x = m.x * Gs[ic + v4 * 4 + 0][jj];
      o.y = m.y * Gs[ic + v4 * 4 + 1][jj];
      o.z = m.z * Gs[ic + v4 * 4 + 2][jj];
      o.w = m.w * Gs[ic + v4 * 4 + 3][jj];
      *(float4*)(op + v4 * 4) = o;
    }
  }
}

// ---------------------------------------------------------------------------
// K4: ctx2b = matrix @ Vp2 (unchanged).
__global__ __launch_bounds__(256) void ctx2_kernel(
    const float* __restrict__ matrix, const float* __restrict__ Vp2,
    __hip_bfloat16* __restrict__ ctx2b) {
  __shared__ __align__(16) float Ms[16][128];
  __shared__ __align__(16) float Vs2t[32][132];
  const int t = threadIdx.x;
  const int b = blockIdx.x >> 5;
  const int s0 = (blockIdx.x & 31) * 16;
  const int dv = t & 31, rg = t >> 5;
  float acc0 = 0.f, acc1 = 0.f;
  for (int kc = 0; kc < 4; kc++) {
    __syncthreads();
#pragma unroll
    for (int it = 0; it < 8; it++) {
      int idx = t + it * 256;
      int r = idx >> 7, cc = idx & 127;
      Ms[r][cc] = matrix[((b << 9) + s0 + r) * 512 + kc * 128 + cc];
    }
#pragma unroll
    for (int it = 0; it < 16; it++) {
      int e = t + it * 256;
      int k = e >> 5, dv2 = e & 31;
      Vs2t[dv2][k] = Vp2[((b << 9) + kc * 128 + k) * 32 + dv2];
    }
    __syncthreads();
    for (int k = 0; k < 128; k += 4) {
      float4 vv = *(const float4*)&Vs2t[dv][k];
      float4 m0 = *(const float4*)&Ms[rg][k];
      float4 m1 = *(const float4*)&Ms[rg + 8][k];
      acc0 += m0.x * vv.x + m0.y * vv.y + m0.z * vv.z + m0.w * vv.w;
      acc1 += m1.x * vv.x + m1.y * vv.y + m1.z * vv.z + m1.w * vv.w;
    }
  }
  ctx2b[((b << 9) + s0 + rg) * 32 + dv] = __float2bfloat16(acc0);
  ctx2b[((b << 9) + s0 + rg + 8) * 32 + dv] = __float2bfloat16(acc1);
}

// ---------------------------------------------------------------------------
// K5: out = LN([ctxb|ctx2b] @ Wfc) (unchanged).
__global__ __launch_bounds__(256) void final_kernel(
    const __hip_bfloat16* __restrict__ ctxb,
    const __hip_bfloat16* __restrict__ ctx2b, const float* __restrict__ Wfc,
    const float* __restrict__ lng, const float* __restrict__ lnb,
    float* __restrict__ out) {
  __shared__ __align__(16) __hip_bfloat16 As[32][40];
  __shared__ __align__(16) __hip_bfloat16 Bs[256][40];
  __shared__ __align__(16) float xs[32][260];
  __shared__ float red2[32][8][2];
  __shared__ float musig[32][2];
  const int tid = threadIdx.x;
  const int m0 = blockIdx.x * 32;
  const int lane = tid & 63, w = tid >> 6;
  const int cl = lane & 15, quad = lane >> 4;
  const int arow = tid >> 3, ak4 = (tid & 7) * 4;

  facc4 acc[2][4];
#pragma unroll
  for (int t = 0; t < 2; t++)
#pragma unroll
    for (int u = 0; u < 4; u++) acc[t][u] = (facc4){0.f, 0.f, 0.f, 0.f};

#pragma unroll 1
  for (int kc = 0; kc < 9; kc++) {
    ushort4 av;
    if (kc < 8)
      av = *(const ushort4*)&ctxb[(m0 + arow) * 256 + kc * 32 + ak4];
    else
      av = *(const ushort4*)&ctx2b[(m0 + arow) * 32 + ak4];
    float wv[32];
#pragma unroll
    for (int j = 0; j < 32; j++) wv[j] = Wfc[(kc * 32 + j) * 256 + tid];
    __syncthreads();
    *(ushort4*)&As[arow][ak4] = av;
    {
      __hip_bfloat16 tw[32];
#pragma unroll
      for (int j = 0; j < 32; j++) tw[j] = __float2bfloat16(wv[j]);
#pragma unroll
      for (int g = 0; g < 4; g++) *(uint4*)&Bs[tid][g * 8] = *(uint4*)&tw[g * 8];
    }
    __syncthreads();
    bfrag8 aA[2], bB[4];
#pragma unroll
    for (int t = 0; t < 2; t++)
      aA[t] = *(const bfrag8*)&As[t * 16 + cl][quad * 8];
#pragma unroll
    for (int u = 0; u < 4; u++)
      bB[u] = *(const bfrag8*)&Bs[w * 64 + u * 16 + cl][quad * 8];
#pragma unroll
    for (int t = 0; t < 2; t++)
#pragma unroll
      for (int u = 0; u < 4; u++)
        acc[t][u] =
            __builtin_amdgcn_mfma_f32_16x16x32_bf16(aA[t], bB[u], acc[t][u], 0, 0, 0);
  }

#pragma unroll
  for (int t = 0; t < 2; t++)
#pragma unroll
    for (int u = 0; u < 4; u++)
#pragma unroll
      for (int reg = 0; reg < 4; reg++)
        xs[t * 16 + quad * 4 + reg][w * 64 + u * 16 + cl] = acc[t][u][reg];
  __syncthreads();

  {
    int r = tid >> 3, c0 = (tid & 7) * 32;
    float s1 = 0.f, s2 = 0.f;
    for (int j = 0; j < 32; j += 4) {
      float4 v = *(const float4*)&xs[r][c0 + j];
      s1 += v.x + v.y + v.z + v.w;
      s2 += v.x * v.x + v.y * v.y + v.z * v.z + v.w * v.w;
    }
    red2[r][tid & 7][0] = s1;
    red2[r][tid & 7][1] = s2;
  }
  __syncthreads();
  if (tid < 32) {
    float s1 = 0.f, s2 = 0.f;
#pragma unroll
    for (int j = 0; j < 8; j++) {
      s1 += red2[tid][j][0];
      s2 += red2[tid][j][1];
    }
    float mu = s1 * (1.f / 256.f);
    float var = s2 * (1.f / 256.f) - mu * mu;
    musig[tid][0] = mu;
    musig[tid][1] = rsqrtf(var + 1e-5f);
  }
  __syncthreads();
  {
    float gt = lng[tid], bt = lnb[tid];
#pragma unroll 4
    for (int r = 0; r < 32; r++)
      out[(m0 + r) * 256 + tid] =
          gt * (xs[r][tid] - musig[r][0]) * musig[r][1] + bt;
  }
}

// ---------------------------------------------------------------------------
extern "C" void kernel_launch(void* const* d_in, const int* in_sizes, int n_in,
                              void* d_out, int out_size, void* d_ws,
                              size_t ws_size, hipStream_t stream) {
  const float* inQ = (const float*)d_in[0];
  const float* inK = (const float*)d_in[1];
  const float* inV = (const float*)d_in[2];
  const void* mask = d_in[3];
  const float* matrix = (const float*)d_in[4];
  const float* Wq = (const float*)d_in[5];
  const float* Wk = (const float*)d_in[6];
  const float* Wv = (const float*)d_in[7];
  const float* Wv2 = (const float*)d_in[8];
  const float* Wfc = (const float*)d_in[9];
  const float* lng = (const float*)d_in[10];
  const float* lnb = (const float*)d_in[11];
  const float* fulng = (const float*)d_in[12];
  const float* fulnb = (const float*)d_in[13];
  const float* fuw1 = (const float*)d_in[14];
  const float* fub1 = (const float*)d_in[15];
  const float* fuw2 = (const float*)d_in[16];
  const float* fub2 = (const float*)d_in[17];

  float* ws = (float*)d_ws;
  __hip_bfloat16* Qb = (__hip_bfloat16*)(ws + OFF_QB);
  __hip_bfloat16* Kb = (__hip_bfloat16*)(ws + OFF_KB);
  __hip_bfloat16* Vt = (__hip_bfloat16*)(ws + OFF_VT);
  float* Vp2 = ws + OFF_VP2;
  __hip_bfloat16* ctxb = (__hip_bfloat16*)(ws + OFF_CTXB);
  __hip_bfloat16* ctx2b = (__hip_bfloat16*)(ws + OFF_CTX2B);
  __hip_bfloat16* gws = (__hip_bfloat16*)(ws + OFF_G);
  unsigned int* flag = (unsigned int*)(ws + OFF_FLAG);
  unsigned long long* pmask = (unsigned long long*)(ws + OFF_PM);
  __hip_bfloat16* Pws = (__hip_bfloat16*)(ws + OFF_PWS);

  float* out = (float*)d_out;
  float* mout = out + BB * SS * DM;

  hipMemsetAsync(flag, 0, 4, stream);
  mask_or_kernel<<<64, 256, 0, stream>>>((const unsigned int*)mask, flag);
  mask_pack_kernel<<<4096, 256, 0, stream>>>(mask, pmask, flag);
  gemm_qkv_kernel<<<1536, 256, 0, stream>>>(inQ, inK, inV, Wq, Wk, Wv, Qb, Kb,
                                            Vt);
  vp2_kernel<<<512, 256, 0, stream>>>(inV, Wv2, Vp2);
  attn_kernel<<<512, 512, 0, stream>>>(Qb, Kb, Vt, pmask, matrix, fulng, fulnb,
                                       fuw1, fub1, fuw2, fub2, ctxb, gws, Pws);
  mout_kernel<<<BB * 64, 256, 0, stream>>>(matrix, gws, mout);
  ctx2_kernel<<<512, 256, 0, stream>>>(matrix, Vp2, ctx2b);
  final_kernel<<<256, 256, 0, stream>>>(ctxb, ctx2b, Wfc, lng, lnb, out);
}

// Round 8
// 405.061 us; speedup vs baseline: 1.2190x; 1.2190x over previous
//
#include <hip/hip_runtime.h>
#include <hip/hip_bf16.h>

#define BB 16
#define SS 512
#define DM 256
#define NH 8

// workspace layout in float units
#define OFF_QB    0         // bf16 Q  [b,s,c]  2097152 elem
#define OFF_KB    1048576   // bf16 K  [b,s,c]
#define OFF_VT    2097152   // bf16 V^T [b,c,s]
#define OFF_VP2   3145728   // f32 [b,s,32]
#define OFF_CTXB  3407872   // bf16 ctx [b,s,256]
#define OFF_CTX2B 4456448   // bf16 ctx2 [b,s,32]
#define OFF_G     4587520   // bf16 g [b,q,k]
#define OFF_FLAG  6684672   // 1 uint
#define OFF_PM    6684674   // packed mask bits, 524288 u64 = 4 MB
// total ws = 7733250 floats ~= 29.5 MB

#define SCALE 0.17677669529663687f
// SCALE * log2(e): exp(SCALE*x) == exp2(KE2*x)
#define KE2 0.2550348623f

typedef __attribute__((ext_vector_type(8))) short bfrag8;  // 8 bf16 (4 VGPR)
typedef __attribute__((ext_vector_type(4))) float facc4;   // MFMA accumulator

// ---------------------------------------------------------------------------
// K0: OR-reduce first 64K words of the mask into *acc (acc pre-zeroed).
__global__ void mask_or_kernel(const unsigned int* __restrict__ w,
                               unsigned int* __restrict__ acc) {
  __shared__ unsigned int sh[256];
  unsigned int a = 0;
  int base = blockIdx.x * 1024;
  for (int i = threadIdx.x; i < 1024; i += 256) a |= w[base + i];
  sh[threadIdx.x] = a;
  __syncthreads();
  for (int s = 128; s > 0; s >>= 1) {
    if (threadIdx.x < s) sh[threadIdx.x] |= sh[threadIdx.x + s];
    __syncthreads();
  }
  if (threadIdx.x == 0) atomicOr(acc, sh[0]);
}

// ---------------------------------------------------------------------------
// K0b: pack mask into bits (1 bit/elem, 4 MB). __ballot of 64 lanes IS the word.
__global__ __launch_bounds__(256) void mask_pack_kernel(
    const void* __restrict__ mask, unsigned long long* __restrict__ pm,
    const unsigned int* __restrict__ orv) {
  const unsigned int rawor = *orv;
  const int flagv = (rawor <= 1u) ? 0 : ((rawor == 0x3F800000u) ? 2 : 1);
  const int lane = threadIdx.x & 63;
  const int wv = threadIdx.x >> 6;
  const int w0 = (blockIdx.x * 4 + wv) * 32;
  const unsigned char* mb = (const unsigned char*)mask;
  const int* mi = (const int*)mask;
  const float* mf = (const float*)mask;
  unsigned long long myw = 0;
#pragma unroll 4
  for (int i = 0; i < 32; i++) {
    long long idx = (long long)(w0 + i) * 64 + lane;
    bool m;
    if (flagv == 1) m = (mb[idx] != 0);
    else if (flagv == 0) m = (mi[idx] != 0);
    else m = (mf[idx] != 0.f);
    unsigned long long bits = __ballot(m);
    if (lane == i) myw = bits;
  }
  if (lane < 32) pm[w0 + lane] = myw;
}

// ---------------------------------------------------------------------------
// K1: MFMA GEMM for Q/K/V projections (unchanged).
__global__ __launch_bounds__(256) void gemm_qkv_kernel(
    const float* __restrict__ inQ, const float* __restrict__ inK,
    const float* __restrict__ inV,
    const float* __restrict__ Wq, const float* __restrict__ Wk,
    const float* __restrict__ Wv,
    __hip_bfloat16* __restrict__ Qb, __hip_bfloat16* __restrict__ Kb,
    __hip_bfloat16* __restrict__ Vt) {
  __shared__ __align__(16) __hip_bfloat16 As[64][40];
  __shared__ __align__(16) __hip_bfloat16 Bs[64][40];
  const int tid = threadIdx.x;
  const int bid = blockIdx.x;
  const int matid = bid >> 9;
  const int mblk = (bid & 511) >> 2;
  const int nblk = bid & 3;
  const int m0 = mblk * 64;
  const int n0 = nblk * 64;
  const float* X = (matid == 0) ? inQ : (matid == 1) ? inK : inV;
  const float* W = (matid == 0) ? Wq : (matid == 1) ? Wk : Wv;

  const int lane = tid & 63;
  const int w = tid >> 6;
  const int wm = w & 1, wn = w >> 1;
  const int cl = lane & 15, quad = lane >> 4;
  const int arow = tid >> 2, ak8 = (tid & 3) * 8;
  const int bn = tid & 63, bk8 = (tid >> 6) * 8;

  facc4 acc[2][2];
#pragma unroll
  for (int t = 0; t < 2; t++)
#pragma unroll
    for (int u = 0; u < 2; u++) acc[t][u] = (facc4){0.f, 0.f, 0.f, 0.f};

#pragma unroll 1
  for (int kc = 0; kc < 8; kc++) {
    float4 x0 = *(const float4*)&X[(m0 + arow) * 256 + kc * 32 + ak8];
    float4 x1 = *(const float4*)&X[(m0 + arow) * 256 + kc * 32 + ak8 + 4];
    float wv[8];
#pragma unroll
    for (int j = 0; j < 8; j++) wv[j] = W[(kc * 32 + bk8 + j) * 256 + n0 + bn];
    __syncthreads();
    {
      __hip_bfloat16 ta[8];
      ta[0] = __float2bfloat16(x0.x); ta[1] = __float2bfloat16(x0.y);
      ta[2] = __float2bfloat16(x0.z); ta[3] = __float2bfloat16(x0.w);
      ta[4] = __float2bfloat16(x1.x); ta[5] = __float2bfloat16(x1.y);
      ta[6] = __float2bfloat16(x1.z); ta[7] = __float2bfloat16(x1.w);
      *(uint4*)&As[arow][ak8] = *(uint4*)ta;
      __hip_bfloat16 tb[8];
#pragma unroll
      for (int j = 0; j < 8; j++) tb[j] = __float2bfloat16(wv[j]);
      *(uint4*)&Bs[bn][bk8] = *(uint4*)tb;
    }
    __syncthreads();
    bfrag8 aA[2], bB[2];
#pragma unroll
    for (int t = 0; t < 2; t++)
      aA[t] = *(const bfrag8*)&As[wm * 32 + t * 16 + cl][quad * 8];
#pragma unroll
    for (int u = 0; u < 2; u++)
      bB[u] = *(const bfrag8*)&Bs[wn * 32 + u * 16 + cl][quad * 8];
#pragma unroll
    for (int t = 0; t < 2; t++)
#pragma unroll
      for (int u = 0; u < 2; u++)
        acc[t][u] =
            __builtin_amdgcn_mfma_f32_16x16x32_bf16(aA[t], bB[u], acc[t][u], 0, 0, 0);
  }

  if (matid < 2) {
    __hip_bfloat16* Y = (matid == 0) ? Qb : Kb;
#pragma unroll
    for (int t = 0; t < 2; t++)
#pragma unroll
      for (int u = 0; u < 2; u++)
#pragma unroll
        for (int reg = 0; reg < 4; reg++)
          Y[(m0 + wm * 32 + t * 16 + quad * 4 + reg) * 256 + n0 + wn * 32 +
            u * 16 + cl] = __float2bfloat16(acc[t][u][reg]);
  } else {
#pragma unroll
    for (int t = 0; t < 2; t++)
#pragma unroll
      for (int u = 0; u < 2; u++) {
        int c = n0 + wn * 32 + u * 16 + cl;
        int mg = m0 + wm * 32 + t * 16 + quad * 4;
        int b = mg >> 9, s = mg & 511;
        __hip_bfloat16 pk[4];
#pragma unroll
        for (int reg = 0; reg < 4; reg++)
          pk[reg] = __float2bfloat16(acc[t][u][reg]);
        *(ushort4*)&Vt[(((b << 8) + c) << 9) + s] = *(ushort4*)pk;
      }
  }
}

// ---------------------------------------------------------------------------
// K1b: Vp2 = inV @ Wv2 (unchanged).
__global__ __launch_bounds__(256) void vp2_kernel(
    const float* __restrict__ inV, const float* __restrict__ Wv2,
    float* __restrict__ Vp2) {
  __shared__ __align__(16) float xs[16][260];
  const int t = threadIdx.x;
  const int r0 = blockIdx.x * 16;
  for (int e = t; e < 16 * 256; e += 256) {
    int r = e >> 8, i = e & 255;
    xs[r][i] = inV[(r0 + r) * 256 + i];
  }
  __syncthreads();
  const int c2 = t & 31, rr = t >> 5;
  float a0 = 0.f, a1 = 0.f;
  for (int i = 0; i < 256; i += 4) {
    float w0 = Wv2[i * 32 + c2], w1 = Wv2[(i + 1) * 32 + c2];
    float w2 = Wv2[(i + 2) * 32 + c2], w3 = Wv2[(i + 3) * 32 + c2];
    float4 xa = *(const float4*)&xs[rr][i];
    float4 xb = *(const float4*)&xs[rr + 8][i];
    a0 += xa.x * w0 + xa.y * w1 + xa.z * w2 + xa.w * w3;
    a1 += xb.x * w0 + xb.y * w1 + xb.z * w2 + xb.w * w3;
  }
  Vp2[(r0 + rr) * 32 + c2] = a0;
  Vp2[(r0 + rr + 8) * 32 + c2] = a1;
}

// ---------------------------------------------------------------------------
// K2: fused attention — R2 champion structure (16 q-rows/block, 1 block/CU,
// full-S unnormalized-e LDS buffer; P MUST stay in LDS — R7 global-P spilled
// to HBM, 515 MB traffic, 2.6x slower). R8 change: T14 issue-early —
// hoist all 16 matrix float4 loads to right after the barrier (latency hides
// under AV MFMAs), fully unroll gate strips (static mrow[] indexing), and move
// ctx stores between AV and gate so they drain during gate VALU.
__global__ __launch_bounds__(512, 2) void attn_kernel(
    const __hip_bfloat16* __restrict__ Qb, const __hip_bfloat16* __restrict__ Kb,
    const __hip_bfloat16* __restrict__ Vt,
    const unsigned long long* __restrict__ pm,
    const float* __restrict__ matrix,
    const float* __restrict__ fulng, const float* __restrict__ fulnb,
    const float* __restrict__ fuw1, const float* __restrict__ fub1,
    const float* __restrict__ fuw2, const float* __restrict__ fub2,
    __hip_bfloat16* __restrict__ ctxb, __hip_bfloat16* __restrict__ gws) {
  // 8*16*520*2 = 133120 B; row stride 1040 B (16B-aligned; 260 mod 32 = 4)
  __shared__ __align__(16) __hip_bfloat16 Sb[NH][16][520];
  __shared__ float inv_s[NH][16];
  __shared__ float gp[80];  // GW1[0..53], S1[54..59], C1[60..65], w2[66..71], b2[72]

  const int tid = threadIdx.x;
  const int lane = tid & 63;
  const int h = tid >> 6;
  const int cl = lane & 15, quad = lane >> 4;
  // XCD swizzle: 2 batches per XCD
  const int b = ((blockIdx.x & 7) << 1) | (blockIdx.x >> 8);
  const int q0 = ((blockIdx.x >> 3) & 31) * 16;

  // gate-param precompute (visible after the main __syncthreads below)
  if (tid < 6) {
    const int j = tid;
    float s1 = 0.f, c1 = fub1[j];
#pragma unroll
    for (int t = 0; t < 9; t++) {
      float w = fuw1[t * 6 + j];
      float gw = fulng[t] * w;
      gp[t * 6 + j] = gw;
      s1 += gw;
      c1 += fulnb[t] * w;
    }
    gp[54 + j] = s1;
    gp[60 + j] = c1;
    gp[66 + j] = fuw2[j];
    if (j == 0) gp[72] = fub2[0];
  }

  // packed-mask base for this (b, h, q0); row r word w at pmb[r*8 + w]
  const unsigned long long* pmb = pm + (((b * NH + h) << 9) + q0) * 8;

  const bfrag8 aQ =
      *(const bfrag8*)&Qb[(((b << 9) + q0 + cl) << 8) + h * 32 + quad * 8];
  const __hip_bfloat16* KbB = &Kb[((b << 9) << 8) + h * 32 + quad * 8];
  const __hip_bfloat16* VtB = &Vt[(((b << 8) + h * 32) << 9)];

  // ---- single pass: scores -> e -> LDS, accumulate row sums ----
  float l[4] = {0.f, 0.f, 0.f, 0.f};
#pragma unroll 2
  for (int w8 = 0; w8 < 8; w8++) {
    unsigned long long mw[4];
#pragma unroll
    for (int r = 0; r < 4; r++)
      mw[r] = pmb[(quad * 4 + r) * 8 + w8] >> cl;  // bit n4*16: col n4*16+cl
#pragma unroll
    for (int n4 = 0; n4 < 4; n4++) {
      const int nt = w8 * 4 + n4;
      bfrag8 bK = *(const bfrag8*)&KbB[(nt * 16 + cl) << 8];
      facc4 cc = {0.f, 0.f, 0.f, 0.f};
      cc = __builtin_amdgcn_mfma_f32_16x16x32_bf16(aQ, bK, cc, 0, 0, 0);
#pragma unroll
      for (int r = 0; r < 4; r++) {
        float e = ((mw[r] >> (n4 * 16)) & 1ULL) ? 0.f : exp2f(KE2 * cc[r]);
        l[r] += e;
        Sb[h][quad * 4 + r][nt * 16 + cl] = __float2bfloat16(e);
      }
    }
  }
#pragma unroll
  for (int r = 0; r < 4; r++)
#pragma unroll
    for (int off = 1; off <= 8; off <<= 1) l[r] += __shfl_xor(l[r], off);
  float invl[4];
#pragma unroll
  for (int r = 0; r < 4; r++) invl[r] = 1.f / l[r];
  if (cl == 0) {
#pragma unroll
    for (int r = 0; r < 4; r++) inv_s[h][quad * 4 + r] = invl[r];
  }
  __syncthreads();  // e of all heads + inv_s + gp visible

  // ---- T14 issue-early: matrix rows for the gate, loaded NOW so the
  // ~200-900 cy latency hides under the AV MFMA loop below ----
  const int gq = tid >> 5;
  const int g32 = (tid & 31) * 4;
  float4 mrow[4];
#pragma unroll
  for (int s = 0; s < 4; s++)
    mrow[s] = *(const float4*)&matrix[((b << 9) + q0 + gq) * 512 + s * 128 + g32];

  // ---- AV: ctx = (sum e*V) * invl (normalization deferred) ----
  facc4 a0 = {0.f, 0.f, 0.f, 0.f}, a1 = {0.f, 0.f, 0.f, 0.f};
#pragma unroll 4
  for (int ks = 0; ks < 16; ks++) {
    bfrag8 aP = *(const bfrag8*)&Sb[h][cl][ks * 32 + quad * 8];
    bfrag8 b0 = *(const bfrag8*)&VtB[(cl << 9) + ks * 32 + quad * 8];
    bfrag8 b1 = *(const bfrag8*)&VtB[((16 + cl) << 9) + ks * 32 + quad * 8];
    a0 = __builtin_amdgcn_mfma_f32_16x16x32_bf16(aP, b0, a0, 0, 0, 0);
    a1 = __builtin_amdgcn_mfma_f32_16x16x32_bf16(aP, b1, a1, 0, 0, 0);
  }

  // ---- ctx stores issued before gate: drain during gate VALU ----
#pragma unroll
  for (int r = 0; r < 4; r++) {
    int row = quad * 4 + r;
    ctxb[((b << 9) + q0 + row) * 256 + h * 32 + cl] =
        __float2bfloat16(a0[r] * invl[r]);
    ctxb[((b << 9) + q0 + row) * 256 + h * 32 + 16 + cl] =
        __float2bfloat16(a1[r] * invl[r]);
  }

  // ---- gate: thread -> (gq, 4 consecutive k), 4 strips fully unrolled ----
#pragma unroll
  for (int s = 0; s < 4; s++) {
    const int k4 = s * 128 + g32;
    float p[NH][4];
#pragma unroll
    for (int hh = 0; hh < NH; hh++) {
      const float iv = inv_s[hh][gq];
      ushort4 sv = *(const ushort4*)&Sb[hh][gq][k4];
      p[hh][0] = __bfloat162float(*(__hip_bfloat16*)&sv.x) * iv;
      p[hh][1] = __bfloat162float(*(__hip_bfloat16*)&sv.y) * iv;
      p[hh][2] = __bfloat162float(*(__hip_bfloat16*)&sv.z) * iv;
      p[hh][3] = __bfloat162float(*(__hip_bfloat16*)&sv.w) * iv;
    }
    const float mcomp[4] = {mrow[s].x, mrow[s].y, mrow[s].z, mrow[s].w};
    __hip_bfloat16 gout[4];
#pragma unroll
    for (int i = 0; i < 4; i++) {
      float v[9];
      v[0] = mcomp[i];
#pragma unroll
      for (int t = 0; t < NH; t++) v[1 + t] = p[t][i];
      float s1 = 0.f, s2 = 0.f;
#pragma unroll
      for (int t = 0; t < 9; t++) {
        s1 += v[t];
        s2 += v[t] * v[t];
      }
      float mu = s1 * (1.f / 9.f);
      float var = s2 * (1.f / 9.f) - mu * mu;
      float inv = rsqrtf(var + 1e-5f);
      float o = gp[72];
#pragma unroll
      for (int j = 0; j < 6; j++) {
        float d = 0.f;
#pragma unroll
        for (int t = 0; t < 9; t++) d += v[t] * gp[t * 6 + j];
        float z = inv * (d - mu * gp[54 + j]) + gp[60 + j];
        z = fmaxf(z, 0.f);
        o += z * gp[66 + j];
      }
      gout[i] = __float2bfloat16(1.f / (1.f + __expf(-o)));
    }
    *(ushort4*)&gws[((b << 9) + q0 + gq) * 512 + k4] = *(ushort4*)gout;
  }
}

// ---------------------------------------------------------------------------
// K3: mout[b,j,i] = matrix[b,j,i] * g[b,i,j] (unchanged).
__global__ __launch_bounds__(256) void mout_kernel(
    const float* __restrict__ matrix, const __hip_bfloat16* __restrict__ g,
    float* __restrict__ mout) {
  __shared__ float Gs[64][65];
  const int tid = threadIdx.x;
  const int b = blockIdx.x >> 6;
  const int j0 = ((blockIdx.x >> 3) & 7) * 64;
  const int i0 = (blockIdx.x & 7) * 64;

  {
    int r = tid >> 2, c0 = (tid & 3) * 16;
    const __hip_bfloat16* gpx = g + (((b << 9) + i0 + r) << 9) + j0 + c0;
    ushort us[16];
    *(uint4*)(us) = *(const uint4*)(gpx);
    *(uint4*)(us + 8) = *(const uint4*)(gpx + 8);
#pragma unroll
    for (int k = 0; k < 16; k++) {
      __hip_bfloat16 hv = *(__hip_bfloat16*)&us[k];
      Gs[r][c0 + k] = __bfloat162float(hv);
    }
  }
  __syncthreads();

  {
    int jj = tid >> 2, ic = (tid & 3) * 16;
    const float* mp = matrix + (((b << 9) + j0 + jj) << 9) + i0 + ic;
    float* op = mout + (((b << 9) + j0 + jj) << 9) + i0 + ic;
#pragma unroll
    for (int v4 = 0; v4 < 4; v4++) {
      float4 m = *(const float4*)(mp + v4 * 4);
      float4 o;
      o.x = m.x * Gs[ic + v4 * 4 + 0][jj];
      o.y = m.y * Gs[ic + v4 * 4 + 1][jj];
      o.z = m.z * Gs[ic + v4 * 4 + 2][jj];
      o.w = m.w * Gs[ic + v4 * 4 + 3][jj];
      *(float4*)(op + v4 * 4) = o;
    }
  }
}

// ---------------------------------------------------------------------------
// K4: ctx2b = matrix @ Vp2 (unchanged).
__global__ __launch_bounds__(256) void ctx2_kernel(
    const float* __restrict__ matrix, const float* __restrict__ Vp2,
    __hip_bfloat16* __restrict__ ctx2b) {
  __shared__ __align__(16) float Ms[16][128];
  __shared__ __align__(16) float Vs2t[32][132];
  const int t = threadIdx.x;
  const int b = blockIdx.x >> 5;
  const int s0 = (blockIdx.x & 31) * 16;
  const int dv = t & 31, rg = t >> 5;
  float acc0 = 0.f, acc1 = 0.f;
  for (int kc = 0; kc < 4; kc++) {
    __syncthreads();
#pragma unroll
    for (int it = 0; it < 8; it++) {
      int idx = t + it * 256;
      int r = idx >> 7, cc = idx & 127;
      Ms[r][cc] = matrix[((b << 9) + s0 + r) * 512 + kc * 128 + cc];
    }
#pragma unroll
    for (int it = 0; it < 16; it++) {
      int e = t + it * 256;
      int k = e >> 5, dv2 = e & 31;
      Vs2t[dv2][k] = Vp2[((b << 9) + kc * 128 + k) * 32 + dv2];
    }
    __syncthreads();
    for (int k = 0; k < 128; k += 4) {
      float4 vv = *(const float4*)&Vs2t[dv][k];
      float4 m0 = *(const float4*)&Ms[rg][k];
      float4 m1 = *(const float4*)&Ms[rg + 8][k];
      acc0 += m0.x * vv.x + m0.y * vv.y + m0.z * vv.z + m0.w * vv.w;
      acc1 += m1.x * vv.x + m1.y * vv.y + m1.z * vv.z + m1.w * vv.w;
    }
  }
  ctx2b[((b << 9) + s0 + rg) * 32 + dv] = __float2bfloat16(acc0);
  ctx2b[((b << 9) + s0 + rg + 8) * 32 + dv] = __float2bfloat16(acc1);
}

// ---------------------------------------------------------------------------
// K5: out = LN([ctxb|ctx2b] @ Wfc) (unchanged).
__global__ __launch_bounds__(256) void final_kernel(
    const __hip_bfloat16* __restrict__ ctxb,
    const __hip_bfloat16* __restrict__ ctx2b, const float* __restrict__ Wfc,
    const float* __restrict__ lng, const float* __restrict__ lnb,
    float* __restrict__ out) {
  __shared__ __align__(16) __hip_bfloat16 As[32][40];
  __shared__ __align__(16) __hip_bfloat16 Bs[256][40];
  __shared__ __align__(16) float xs[32][260];
  __shared__ float red2[32][8][2];
  __shared__ float musig[32][2];
  const int tid = threadIdx.x;
  const int m0 = blockIdx.x * 32;
  const int lane = tid & 63, w = tid >> 6;
  const int cl = lane & 15, quad = lane >> 4;
  const int arow = tid >> 3, ak4 = (tid & 7) * 4;

  facc4 acc[2][4];
#pragma unroll
  for (int t = 0; t < 2; t++)
#pragma unroll
    for (int u = 0; u < 4; u++) acc[t][u] = (facc4){0.f, 0.f, 0.f, 0.f};

#pragma unroll 1
  for (int kc = 0; kc < 9; kc++) {
    ushort4 av;
    if (kc < 8)
      av = *(const ushort4*)&ctxb[(m0 + arow) * 256 + kc * 32 + ak4];
    else
      av = *(const ushort4*)&ctx2b[(m0 + arow) * 32 + ak4];
    float wv[32];
#pragma unroll
    for (int j = 0; j < 32; j++) wv[j] = Wfc[(kc * 32 + j) * 256 + tid];
    __syncthreads();
    *(ushort4*)&As[arow][ak4] = av;
    {
      __hip_bfloat16 tw[32];
#pragma unroll
      for (int j = 0; j < 32; j++) tw[j] = __float2bfloat16(wv[j]);
#pragma unroll
      for (int g = 0; g < 4; g++) *(uint4*)&Bs[tid][g * 8] = *(uint4*)&tw[g * 8];
    }
    __syncthreads();
    bfrag8 aA[2], bB[4];
#pragma unroll
    for (int t = 0; t < 2; t++)
      aA[t] = *(const bfrag8*)&As[t * 16 + cl][quad * 8];
#pragma unroll
    for (int u = 0; u < 4; u++)
      bB[u] = *(const bfrag8*)&Bs[w * 64 + u * 16 + cl][quad * 8];
#pragma unroll
    for (int t = 0; t < 2; t++)
#pragma unroll
      for (int u = 0; u < 4; u++)
        acc[t][u] =
            __builtin_amdgcn_mfma_f32_16x16x32_bf16(aA[t], bB[u], acc[t][u], 0, 0, 0);
  }

#pragma unroll
  for (int t = 0; t < 2; t++)
#pragma unroll
    for (int u = 0; u < 4; u++)
#pragma unroll
      for (int reg = 0; reg < 4; reg++)
        xs[t * 16 + quad * 4 + reg][w * 64 + u * 16 + cl] = acc[t][u][reg];
  __syncthreads();

  {
    int r = tid >> 3, c0 = (tid & 7) * 32;
    float s1 = 0.f, s2 = 0.f;
    for (int j = 0; j < 32; j += 4) {
      float4 v = *(const float4*)&xs[r][c0 + j];
      s1 += v.x + v.y + v.z + v.w;
      s2 += v.x * v.x + v.y * v.y + v.z * v.z + v.w * v.w;
    }
    red2[r][tid & 7][0] = s1;
    red2[r][tid & 7][1] = s2;
  }
  __syncthreads();
  if (tid < 32) {
    float s1 = 0.f, s2 = 0.f;
#pragma unroll
    for (int j = 0; j < 8; j++) {
      s1 += red2[tid][j][0];
      s2 += red2[tid][j][1];
    }
    float mu = s1 * (1.f / 256.f);
    float var = s2 * (1.f / 256.f) - mu * mu;
    musig[tid][0] = mu;
    musig[tid][1] = rsqrtf(var + 1e-5f);
  }
  __syncthreads();
  {
    float gt = lng[tid], bt = lnb[tid];
#pragma unroll 4
    for (int r = 0; r < 32; r++)
      out[(m0 + r) * 256 + tid] =
          gt * (xs[r][tid] - musig[r][0]) * musig[r][1] + bt;
  }
}

// ---------------------------------------------------------------------------
extern "C" void kernel_launch(void* const* d_in, const int* in_sizes, int n_in,
                              void* d_out, int out_size, void* d_ws,
                              size_t ws_size, hipStream_t stream) {
  const float* inQ = (const float*)d_in[0];
  const float* inK = (const float*)d_in[1];
  const float* inV = (const float*)d_in[2];
  const void* mask = d_in[3];
  const float* matrix = (const float*)d_in[4];
  const float* Wq = (const float*)d_in[5];
  const float* Wk = (const float*)d_in[6];
  const float* Wv = (const float*)d_in[7];
  const float* Wv2 = (const float*)d_in[8];
  const float* Wfc = (const float*)d_in[9];
  const float* lng = (const float*)d_in[10];
  const float* lnb = (const float*)d_in[11];
  const float* fulng = (const float*)d_in[12];
  const float* fulnb = (const float*)d_in[13];
  const float* fuw1 = (const float*)d_in[14];
  const float* fub1 = (const float*)d_in[15];
  const float* fuw2 = (const float*)d_in[16];
  const float* fub2 = (const float*)d_in[17];

  float* ws = (float*)d_ws;
  __hip_bfloat16* Qb = (__hip_bfloat16*)(ws + OFF_QB);
  __hip_bfloat16* Kb = (__hip_bfloat16*)(ws + OFF_KB);
  __hip_bfloat16* Vt = (__hip_bfloat16*)(ws + OFF_VT);
  float* Vp2 = ws + OFF_VP2;
  __hip_bfloat16* ctxb = (__hip_bfloat16*)(ws + OFF_CTXB);
  __hip_bfloat16* ctx2b = (__hip_bfloat16*)(ws + OFF_CTX2B);
  __hip_bfloat16* gws = (__hip_bfloat16*)(ws + OFF_G);
  unsigned int* flag = (unsigned int*)(ws + OFF_FLAG);
  unsigned long long* pmask = (unsigned long long*)(ws + OFF_PM);

  float* out = (float*)d_out;
  float* mout = out + BB * SS * DM;

  hipMemsetAsync(flag, 0, 4, stream);
  mask_or_kernel<<<64, 256, 0, stream>>>((const unsigned int*)mask, flag);
  mask_pack_kernel<<<4096, 256, 0, stream>>>(mask, pmask, flag);
  gemm_qkv_kernel<<<1536, 256, 0, stream>>>(inQ, inK, inV, Wq, Wk, Wv, Qb, Kb,
                                            Vt);
  vp2_kernel<<<512, 256, 0, stream>>>(inV, Wv2, Vp2);
  attn_kernel<<<512, 512, 0, stream>>>(Qb, Kb, Vt, pmask, matrix, fulng, fulnb,
                                       fuw1, fub1, fuw2, fub2, ctxb, gws);
  mout_kernel<<<BB * 64, 256, 0, stream>>>(matrix, gws, mout);
  ctx2_kernel<<<512, 256, 0, stream>>>(matrix, Vp2, ctx2b);
  final_kernel<<<256, 256, 0, stream>>>(ctxb, ctx2b, Wfc, lng, lnb, out);
}

// Round 9
// 381.751 us; speedup vs baseline: 1.2934x; 1.0611x over previous
//
#include <hip/hip_runtime.h>
#include <hip/hip_bf16.h>

#define BB 16
#define SS 512
#define DM 256
#define NH 8

// workspace layout in float units
#define OFF_QB    0         // bf16 Q  [b,s,c]  2097152 elem
#define OFF_KB    1048576   // bf16 K  [b,s,c]
#define OFF_VT    2097152   // bf16 V^T [b,c,s]
#define OFF_VP2   3145728   // f32 [b,s,32]
#define OFF_CTXB  3407872   // bf16 ctx [b,s,256]
#define OFF_CTX2B 4456448   // bf16 ctx2 [b,s,32]
#define OFF_G     4587520   // bf16 g [b,q,k]
#define OFF_FLAG  6684672   // 1 uint
#define OFF_PM    6684674   // packed mask bits, 524288 u64 = 4 MB
// total ws = 7733250 floats ~= 29.5 MB

#define SCALE 0.17677669529663687f
// SCALE * log2(e): exp(SCALE*x) == exp2(KE2*x)
#define KE2 0.2550348623f

typedef __attribute__((ext_vector_type(8))) short bfrag8;  // 8 bf16 (4 VGPR)
typedef __attribute__((ext_vector_type(4))) float facc4;   // MFMA accumulator

// ---------------------------------------------------------------------------
// K0: OR-reduce first 64K words of the mask into *acc (fallback path only).
__global__ void mask_or_kernel(const unsigned int* __restrict__ w,
                               unsigned int* __restrict__ acc) {
  __shared__ unsigned int sh[256];
  unsigned int a = 0;
  int base = blockIdx.x * 1024;
  for (int i = threadIdx.x; i < 1024; i += 256) a |= w[base + i];
  sh[threadIdx.x] = a;
  __syncthreads();
  for (int s = 128; s > 0; s >>= 1) {
    if (threadIdx.x < s) sh[threadIdx.x] |= sh[threadIdx.x + s];
    __syncthreads();
  }
  if (threadIdx.x == 0) atomicOr(acc, sh[0]);
}

// ---------------------------------------------------------------------------
// K0b: flagged pack (fallback; handles byte/int/float via runtime flag).
__global__ __launch_bounds__(256) void mask_pack_kernel(
    const void* __restrict__ mask, unsigned long long* __restrict__ pm,
    const unsigned int* __restrict__ orv) {
  const unsigned int rawor = *orv;
  const int flagv = (rawor <= 1u) ? 0 : ((rawor == 0x3F800000u) ? 2 : 1);
  const int lane = threadIdx.x & 63;
  const int wv = threadIdx.x >> 6;
  const int w0 = (blockIdx.x * 4 + wv) * 32;
  const unsigned char* mb = (const unsigned char*)mask;
  const int* mi = (const int*)mask;
  const float* mf = (const float*)mask;
  unsigned long long myw = 0;
#pragma unroll 4
  for (int i = 0; i < 32; i++) {
    long long idx = (long long)(w0 + i) * 64 + lane;
    bool m;
    if (flagv == 1) m = (mb[idx] != 0);
    else if (flagv == 0) m = (mi[idx] != 0);
    else m = (mf[idx] != 0.f);
    unsigned long long bits = __ballot(m);
    if (lane == i) myw = bits;
  }
  if (lane < 32) pm[w0 + lane] = myw;
}

// K0c: flagless pack for 4-byte masks (proven 4-byte by R1 FETCH=134MB).
// int 0/1 and float 0/1.0 are both exactly (word != 0).
__global__ __launch_bounds__(256) void mask_pack4_kernel(
    const unsigned int* __restrict__ mask, unsigned long long* __restrict__ pm) {
  const int lane = threadIdx.x & 63;
  const int wv = threadIdx.x >> 6;
  const int w0 = (blockIdx.x * 4 + wv) * 32;
  unsigned long long myw = 0;
#pragma unroll 4
  for (int i = 0; i < 32; i++) {
    unsigned int v = mask[(long long)(w0 + i) * 64 + lane];
    unsigned long long bits = __ballot(v != 0u);
    if (lane == i) myw = bits;
  }
  if (lane < 32) pm[w0 + lane] = myw;
}

// ---------------------------------------------------------------------------
// K1: gemm_qkv + vp2 concatenated (one dispatch, bodies unchanged).
// blocks 0..1535: Q/K/V projection GEMM.  blocks 1536..2047: Vp2 = inV @ Wv2.
// Shared LDS buffer: gemm needs 10240 B (As+Bs), vp2 needs 16640 B (xs).
__global__ __launch_bounds__(256) void gemm_qkv_vp2_kernel(
    const float* __restrict__ inQ, const float* __restrict__ inK,
    const float* __restrict__ inV,
    const float* __restrict__ Wq, const float* __restrict__ Wk,
    const float* __restrict__ Wv, const float* __restrict__ Wv2,
    __hip_bfloat16* __restrict__ Qb, __hip_bfloat16* __restrict__ Kb,
    __hip_bfloat16* __restrict__ Vt, float* __restrict__ Vp2) {
  __shared__ __align__(16) char smem[16640];
  const int tid = threadIdx.x;

  if (blockIdx.x < 1536) {
    // ---- gemm_qkv body (unchanged) ----
    auto As = reinterpret_cast<__hip_bfloat16(*)[40]>(smem);          // 64x40
    auto Bs = reinterpret_cast<__hip_bfloat16(*)[40]>(smem + 5120);   // 64x40
    const int bid = blockIdx.x;
    const int matid = bid >> 9;
    const int mblk = (bid & 511) >> 2;
    const int nblk = bid & 3;
    const int m0 = mblk * 64;
    const int n0 = nblk * 64;
    const float* X = (matid == 0) ? inQ : (matid == 1) ? inK : inV;
    const float* W = (matid == 0) ? Wq : (matid == 1) ? Wk : Wv;

    const int lane = tid & 63;
    const int w = tid >> 6;
    const int wm = w & 1, wn = w >> 1;
    const int cl = lane & 15, quad = lane >> 4;
    const int arow = tid >> 2, ak8 = (tid & 3) * 8;
    const int bn = tid & 63, bk8 = (tid >> 6) * 8;

    facc4 acc[2][2];
#pragma unroll
    for (int t = 0; t < 2; t++)
#pragma unroll
      for (int u = 0; u < 2; u++) acc[t][u] = (facc4){0.f, 0.f, 0.f, 0.f};

#pragma unroll 1
    for (int kc = 0; kc < 8; kc++) {
      float4 x0 = *(const float4*)&X[(m0 + arow) * 256 + kc * 32 + ak8];
      float4 x1 = *(const float4*)&X[(m0 + arow) * 256 + kc * 32 + ak8 + 4];
      float wv[8];
#pragma unroll
      for (int j = 0; j < 8; j++)
        wv[j] = W[(kc * 32 + bk8 + j) * 256 + n0 + bn];
      __syncthreads();
      {
        __hip_bfloat16 ta[8];
        ta[0] = __float2bfloat16(x0.x); ta[1] = __float2bfloat16(x0.y);
        ta[2] = __float2bfloat16(x0.z); ta[3] = __float2bfloat16(x0.w);
        ta[4] = __float2bfloat16(x1.x); ta[5] = __float2bfloat16(x1.y);
        ta[6] = __float2bfloat16(x1.z); ta[7] = __float2bfloat16(x1.w);
        *(uint4*)&As[arow][ak8] = *(uint4*)ta;
        __hip_bfloat16 tb[8];
#pragma unroll
        for (int j = 0; j < 8; j++) tb[j] = __float2bfloat16(wv[j]);
        *(uint4*)&Bs[bn][bk8] = *(uint4*)tb;
      }
      __syncthreads();
      bfrag8 aA[2], bB[2];
#pragma unroll
      for (int t = 0; t < 2; t++)
        aA[t] = *(const bfrag8*)&As[wm * 32 + t * 16 + cl][quad * 8];
#pragma unroll
      for (int u = 0; u < 2; u++)
        bB[u] = *(const bfrag8*)&Bs[wn * 32 + u * 16 + cl][quad * 8];
#pragma unroll
      for (int t = 0; t < 2; t++)
#pragma unroll
        for (int u = 0; u < 2; u++)
          acc[t][u] = __builtin_amdgcn_mfma_f32_16x16x32_bf16(aA[t], bB[u],
                                                             acc[t][u], 0, 0, 0);
    }

    if (matid < 2) {
      __hip_bfloat16* Y = (matid == 0) ? Qb : Kb;
#pragma unroll
      for (int t = 0; t < 2; t++)
#pragma unroll
        for (int u = 0; u < 2; u++)
#pragma unroll
          for (int reg = 0; reg < 4; reg++)
            Y[(m0 + wm * 32 + t * 16 + quad * 4 + reg) * 256 + n0 + wn * 32 +
              u * 16 + cl] = __float2bfloat16(acc[t][u][reg]);
    } else {
#pragma unroll
      for (int t = 0; t < 2; t++)
#pragma unroll
        for (int u = 0; u < 2; u++) {
          int c = n0 + wn * 32 + u * 16 + cl;
          int mg = m0 + wm * 32 + t * 16 + quad * 4;
          int b = mg >> 9, s = mg & 511;
          __hip_bfloat16 pk[4];
#pragma unroll
          for (int reg = 0; reg < 4; reg++)
            pk[reg] = __float2bfloat16(acc[t][u][reg]);
          *(ushort4*)&Vt[(((b << 8) + c) << 9) + s] = *(ushort4*)pk;
        }
    }
  } else {
    // ---- vp2 body (unchanged) ----
    auto xs = reinterpret_cast<float(*)[260]>(smem);  // 16x260
    const int r0 = (blockIdx.x - 1536) * 16;
    for (int e = tid; e < 16 * 256; e += 256) {
      int r = e >> 8, i = e & 255;
      xs[r][i] = inV[(r0 + r) * 256 + i];
    }
    __syncthreads();
    const int c2 = tid & 31, rr = tid >> 5;
    float a0 = 0.f, a1 = 0.f;
    for (int i = 0; i < 256; i += 4) {
      float w0 = Wv2[i * 32 + c2], w1 = Wv2[(i + 1) * 32 + c2];
      float w2 = Wv2[(i + 2) * 32 + c2], w3 = Wv2[(i + 3) * 32 + c2];
      float4 xa = *(const float4*)&xs[rr][i];
      float4 xb = *(const float4*)&xs[rr + 8][i];
      a0 += xa.x * w0 + xa.y * w1 + xa.z * w2 + xa.w * w3;
      a1 += xb.x * w0 + xb.y * w1 + xb.z * w2 + xb.w * w3;
    }
    Vp2[(r0 + rr) * 32 + c2] = a0;
    Vp2[(r0 + rr + 8) * 32 + c2] = a1;
  }
}

// ---------------------------------------------------------------------------
// K2: fused attention — EXACT R2 champion (386.6 µs config): 16 q-rows/block,
// 1 block/CU, full-S unnormalized-e LDS buffer; QK unroll 2, AV unroll 4,
// gate unroll 1. R8's hoist/full-unroll caused scratch spills (WRITE 12->98MB)
// — reverted. P must stay in LDS (R7 global-P: HBM blowup).
__global__ __launch_bounds__(512, 2) void attn_kernel(
    const __hip_bfloat16* __restrict__ Qb, const __hip_bfloat16* __restrict__ Kb,
    const __hip_bfloat16* __restrict__ Vt,
    const unsigned long long* __restrict__ pm,
    const float* __restrict__ matrix,
    const float* __restrict__ fulng, const float* __restrict__ fulnb,
    const float* __restrict__ fuw1, const float* __restrict__ fub1,
    const float* __restrict__ fuw2, const float* __restrict__ fub2,
    __hip_bfloat16* __restrict__ ctxb, __hip_bfloat16* __restrict__ gws) {
  // 8*16*520*2 = 133120 B; row stride 1040 B (16B-aligned; 260 mod 32 = 4)
  __shared__ __align__(16) __hip_bfloat16 Sb[NH][16][520];
  __shared__ float inv_s[NH][16];
  __shared__ float gp[80];  // GW1[0..53], S1[54..59], C1[60..65], w2[66..71], b2[72]

  const int tid = threadIdx.x;
  const int lane = tid & 63;
  const int h = tid >> 6;
  const int cl = lane & 15, quad = lane >> 4;
  // XCD swizzle: 2 batches per XCD
  const int b = ((blockIdx.x & 7) << 1) | (blockIdx.x >> 8);
  const int q0 = ((blockIdx.x >> 3) & 31) * 16;

  // gate-param precompute (visible after the main __syncthreads below)
  if (tid < 6) {
    const int j = tid;
    float s1 = 0.f, c1 = fub1[j];
#pragma unroll
    for (int t = 0; t < 9; t++) {
      float w = fuw1[t * 6 + j];
      float gw = fulng[t] * w;
      gp[t * 6 + j] = gw;
      s1 += gw;
      c1 += fulnb[t] * w;
    }
    gp[54 + j] = s1;
    gp[60 + j] = c1;
    gp[66 + j] = fuw2[j];
    if (j == 0) gp[72] = fub2[0];
  }

  // packed-mask base for this (b, h, q0); row r word w at pmb[r*8 + w]
  const unsigned long long* pmb = pm + (((b * NH + h) << 9) + q0) * 8;

  const bfrag8 aQ =
      *(const bfrag8*)&Qb[(((b << 9) + q0 + cl) << 8) + h * 32 + quad * 8];
  const __hip_bfloat16* KbB = &Kb[((b << 9) << 8) + h * 32 + quad * 8];
  const __hip_bfloat16* VtB = &Vt[(((b << 8) + h * 32) << 9)];

  // ---- single pass: scores -> e -> LDS, accumulate row sums ----
  float l[4] = {0.f, 0.f, 0.f, 0.f};
#pragma unroll 2
  for (int w8 = 0; w8 < 8; w8++) {
    unsigned long long mw[4];
#pragma unroll
    for (int r = 0; r < 4; r++)
      mw[r] = pmb[(quad * 4 + r) * 8 + w8] >> cl;  // bit n4*16: col n4*16+cl
#pragma unroll
    for (int n4 = 0; n4 < 4; n4++) {
      const int nt = w8 * 4 + n4;
      bfrag8 bK = *(const bfrag8*)&KbB[(nt * 16 + cl) << 8];
      facc4 cc = {0.f, 0.f, 0.f, 0.f};
      cc = __builtin_amdgcn_mfma_f32_16x16x32_bf16(aQ, bK, cc, 0, 0, 0);
#pragma unroll
      for (int r = 0; r < 4; r++) {
        float e = ((mw[r] >> (n4 * 16)) & 1ULL) ? 0.f : exp2f(KE2 * cc[r]);
        l[r] += e;
        Sb[h][quad * 4 + r][nt * 16 + cl] = __float2bfloat16(e);
      }
    }
  }
#pragma unroll
  for (int r = 0; r < 4; r++)
#pragma unroll
    for (int off = 1; off <= 8; off <<= 1) l[r] += __shfl_xor(l[r], off);
  float invl[4];
#pragma unroll
  for (int r = 0; r < 4; r++) invl[r] = 1.f / l[r];
  if (cl == 0) {
#pragma unroll
    for (int r = 0; r < 4; r++) inv_s[h][quad * 4 + r] = invl[r];
  }
  __syncthreads();  // e of all heads + inv_s + gp visible

  // ---- AV: ctx = (sum e*V) * invl (normalization deferred to epilogue) ----
  facc4 a0 = {0.f, 0.f, 0.f, 0.f}, a1 = {0.f, 0.f, 0.f, 0.f};
#pragma unroll 4
  for (int ks = 0; ks < 16; ks++) {
    bfrag8 aP = *(const bfrag8*)&Sb[h][cl][ks * 32 + quad * 8];
    bfrag8 b0 = *(const bfrag8*)&VtB[(cl << 9) + ks * 32 + quad * 8];
    bfrag8 b1 = *(const bfrag8*)&VtB[((16 + cl) << 9) + ks * 32 + quad * 8];
    a0 = __builtin_amdgcn_mfma_f32_16x16x32_bf16(aP, b0, a0, 0, 0, 0);
    a1 = __builtin_amdgcn_mfma_f32_16x16x32_bf16(aP, b1, a1, 0, 0, 0);
  }

  // ---- gate: thread -> (gq, 4 consecutive k), 4 strips of 128 cols ----
  {
    const int gq = tid >> 5;
    const int g32 = (tid & 31) * 4;
#pragma unroll 1
    for (int s = 0; s < 4; s++) {
      const int k4 = s * 128 + g32;
      float4 mrow =
          *(const float4*)&matrix[((b << 9) + q0 + gq) * 512 + k4];
      float p[NH][4];
#pragma unroll
      for (int hh = 0; hh < NH; hh++) {
        const float iv = inv_s[hh][gq];
        ushort4 sv = *(const ushort4*)&Sb[hh][gq][k4];
        p[hh][0] = __bfloat162float(*(__hip_bfloat16*)&sv.x) * iv;
        p[hh][1] = __bfloat162float(*(__hip_bfloat16*)&sv.y) * iv;
        p[hh][2] = __bfloat162float(*(__hip_bfloat16*)&sv.z) * iv;
        p[hh][3] = __bfloat162float(*(__hip_bfloat16*)&sv.w) * iv;
      }
      const float mcomp[4] = {mrow.x, mrow.y, mrow.z, mrow.w};
      __hip_bfloat16 gout[4];
#pragma unroll
      for (int i = 0; i < 4; i++) {
        float v[9];
        v[0] = mcomp[i];
#pragma unroll
        for (int t = 0; t < NH; t++) v[1 + t] = p[t][i];
        float s1 = 0.f, s2 = 0.f;
#pragma unroll
        for (int t = 0; t < 9; t++) {
          s1 += v[t];
          s2 += v[t] * v[t];
        }
        float mu = s1 * (1.f / 9.f);
        float var = s2 * (1.f / 9.f) - mu * mu;
        float inv = rsqrtf(var + 1e-5f);
        float o = gp[72];
#pragma unroll
        for (int j = 0; j < 6; j++) {
          float d = 0.f;
#pragma unroll
          for (int t = 0; t < 9; t++) d += v[t] * gp[t * 6 + j];
          float z = inv * (d - mu * gp[54 + j]) + gp[60 + j];
          z = fmaxf(z, 0.f);
          o += z * gp[66 + j];
        }
        gout[i] = __float2bfloat16(1.f / (1.f + __expf(-o)));
      }
      *(ushort4*)&gws[((b << 9) + q0 + gq) * 512 + k4] = *(ushort4*)gout;
    }
  }

  // ---- epilogue: scale + write ctx ----
#pragma unroll
  for (int r = 0; r < 4; r++) {
    int row = quad * 4 + r;
    ctxb[((b << 9) + q0 + row) * 256 + h * 32 + cl] =
        __float2bfloat16(a0[r] * invl[r]);
    ctxb[((b << 9) + q0 + row) * 256 + h * 32 + 16 + cl] =
        __float2bfloat16(a1[r] * invl[r]);
  }
}

// ---------------------------------------------------------------------------
// K3: mout + ctx2 concatenated (one dispatch, bodies unchanged).
// blocks 0..1023: mout[b,j,i] = matrix[b,j,i] * g[b,i,j].
// blocks 1024..1535: ctx2b = matrix @ Vp2.
// Shared LDS: mout needs 16640 B (Gs), ctx2 needs 25088 B (Ms+Vs2t).
__global__ __launch_bounds__(256) void mout_ctx2_kernel(
    const float* __restrict__ matrix, const __hip_bfloat16* __restrict__ g,
    float* __restrict__ mout, const float* __restrict__ Vp2,
    __hip_bfloat16* __restrict__ ctx2b) {
  __shared__ __align__(16) char smem[25088];
  const int tid = threadIdx.x;

  if (blockIdx.x < 1024) {
    // ---- mout body (unchanged) ----
    auto Gs = reinterpret_cast<float(*)[65]>(smem);  // 64x65
    const int b = blockIdx.x >> 6;
    const int j0 = ((blockIdx.x >> 3) & 7) * 64;
    const int i0 = (blockIdx.x & 7) * 64;

    {
      int r = tid >> 2, c0 = (tid & 3) * 16;
      const __hip_bfloat16* gpx = g + (((b << 9) + i0 + r) << 9) + j0 + c0;
      ushort us[16];
      *(uint4*)(us) = *(const uint4*)(gpx);
      *(uint4*)(us + 8) = *(const uint4*)(gpx + 8);
#pragma unroll
      for (int k = 0; k < 16; k++) {
        __hip_bfloat16 hv = *(__hip_bfloat16*)&us[k];
        Gs[r][c0 + k] = __bfloat162float(hv);
      }
    }
    __syncthreads();

    {
      int jj = tid >> 2, ic = (tid & 3) * 16;
      const float* mp = matrix + (((b << 9) + j0 + jj) << 9) + i0 + ic;
      float* op = mout + (((b << 9) + j0 + jj) << 9) + i0 + ic;
#pragma unroll
      for (int v4 = 0; v4 < 4; v4++) {
        float4 m = *(const float4*)(mp + v4 * 4);
        float4 o;
        o.x = m.x * Gs[ic + v4 * 4 + 0][jj];
        o.y = m.y * Gs[ic + v4 * 4 + 1][jj];
        o.z = m.z * Gs[ic + v4 * 4 + 2][jj];
        o.w = m.w * Gs[ic + v4 * 4 + 3][jj];
        *(float4*)(op + v4 * 4) = o;
      }
    }
  } else {
    // ---- ctx2 body (unchanged) ----
    auto Ms = reinterpret_cast<float(*)[128]>(smem);            // 16x128
    auto Vs2t = reinterpret_cast<float(*)[132]>(smem + 8192);   // 32x132
    const int cid = blockIdx.x - 1024;
    const int b = cid >> 5;
    const int s0 = (cid & 31) * 16;
    const int dv = tid & 31, rg = tid >> 5;
    float acc0 = 0.f, acc1 = 0.f;
    for (int kc = 0; kc < 4; kc++) {
      __syncthreads();
#pragma unroll
      for (int it = 0; it < 8; it++) {
        int idx = tid + it * 256;
        int r = idx >> 7, cc = idx & 127;
        Ms[r][cc] = matrix[((b << 9) + s0 + r) * 512 + kc * 128 + cc];
      }
#pragma unroll
      for (int it = 0; it < 16; it++) {
        int e = tid + it * 256;
        int k = e >> 5, dv2 = e & 31;
        Vs2t[dv2][k] = Vp2[((b << 9) + kc * 128 + k) * 32 + dv2];
      }
      __syncthreads();
      for (int k = 0; k < 128; k += 4) {
        float4 vv = *(const float4*)&Vs2t[dv][k];
        float4 m0 = *(const float4*)&Ms[rg][k];
        float4 m1 = *(const float4*)&Ms[rg + 8][k];
        acc0 += m0.x * vv.x + m0.y * vv.y + m0.z * vv.z + m0.w * vv.w;
        acc1 += m1.x * vv.x + m1.y * vv.y + m1.z * vv.z + m1.w * vv.w;
      }
    }
    ctx2b[((b << 9) + s0 + rg) * 32 + dv] = __float2bfloat16(acc0);
    ctx2b[((b << 9) + s0 + rg + 8) * 32 + dv] = __float2bfloat16(acc1);
  }
}

// ---------------------------------------------------------------------------
// K5: out = LN([ctxb|ctx2b] @ Wfc) (unchanged).
__global__ __launch_bounds__(256) void final_kernel(
    const __hip_bfloat16* __restrict__ ctxb,
    const __hip_bfloat16* __restrict__ ctx2b, const float* __restrict__ Wfc,
    const float* __restrict__ lng, const float* __restrict__ lnb,
    float* __restrict__ out) {
  __shared__ __align__(16) __hip_bfloat16 As[32][40];
  __shared__ __align__(16) __hip_bfloat16 Bs[256][40];
  __shared__ __align__(16) float xs[32][260];
  __shared__ float red2[32][8][2];
  __shared__ float musig[32][2];
  const int tid = threadIdx.x;
  const int m0 = blockIdx.x * 32;
  const int lane = tid & 63, w = tid >> 6;
  const int cl = lane & 15, quad = lane >> 4;
  const int arow = tid >> 3, ak4 = (tid & 7) * 4;

  facc4 acc[2][4];
#pragma unroll
  for (int t = 0; t < 2; t++)
#pragma unroll
    for (int u = 0; u < 4; u++) acc[t][u] = (facc4){0.f, 0.f, 0.f, 0.f};

#pragma unroll 1
  for (int kc = 0; kc < 9; kc++) {
    ushort4 av;
    if (kc < 8)
      av = *(const ushort4*)&ctxb[(m0 + arow) * 256 + kc * 32 + ak4];
    else
      av = *(const ushort4*)&ctx2b[(m0 + arow) * 32 + ak4];
    float wv[32];
#pragma unroll
    for (int j = 0; j < 32; j++) wv[j] = Wfc[(kc * 32 + j) * 256 + tid];
    __syncthreads();
    *(ushort4*)&As[arow][ak4] = av;
    {
      __hip_bfloat16 tw[32];
#pragma unroll
      for (int j = 0; j < 32; j++) tw[j] = __float2bfloat16(wv[j]);
#pragma unroll
      for (int g = 0; g < 4; g++) *(uint4*)&Bs[tid][g * 8] = *(uint4*)&tw[g * 8];
    }
    __syncthreads();
    bfrag8 aA[2], bB[4];
#pragma unroll
    for (int t = 0; t < 2; t++)
      aA[t] = *(const bfrag8*)&As[t * 16 + cl][quad * 8];
#pragma unroll
    for (int u = 0; u < 4; u++)
      bB[u] = *(const bfrag8*)&Bs[w * 64 + u * 16 + cl][quad * 8];
#pragma unroll
    for (int t = 0; t < 2; t++)
#pragma unroll
      for (int u = 0; u < 4; u++)
        acc[t][u] =
            __builtin_amdgcn_mfma_f32_16x16x32_bf16(aA[t], bB[u], acc[t][u], 0, 0, 0);
  }

#pragma unroll
  for (int t = 0; t < 2; t++)
#pragma unroll
    for (int u = 0; u < 4; u++)
#pragma unroll
      for (int reg = 0; reg < 4; reg++)
        xs[t * 16 + quad * 4 + reg][w * 64 + u * 16 + cl] = acc[t][u][reg];
  __syncthreads();

  {
    int r = tid >> 3, c0 = (tid & 7) * 32;
    float s1 = 0.f, s2 = 0.f;
    for (int j = 0; j < 32; j += 4) {
      float4 v = *(const float4*)&xs[r][c0 + j];
      s1 += v.x + v.y + v.z + v.w;
      s2 += v.x * v.x + v.y * v.y + v.z * v.z + v.w * v.w;
    }
    red2[r][tid & 7][0] = s1;
    red2[r][tid & 7][1] = s2;
  }
  __syncthreads();
  if (tid < 32) {
    float s1 = 0.f, s2 = 0.f;
#pragma unroll
    for (int j = 0; j < 8; j++) {
      s1 += red2[tid][j][0];
      s2 += red2[tid][j][1];
    }
    float mu = s1 * (1.f / 256.f);
    float var = s2 * (1.f / 256.f) - mu * mu;
    musig[tid][0] = mu;
    musig[tid][1] = rsqrtf(var + 1e-5f);
  }
  __syncthreads();
  {
    float gt = lng[tid], bt = lnb[tid];
#pragma unroll 4
    for (int r = 0; r < 32; r++)
      out[(m0 + r) * 256 + tid] =
          gt * (xs[r][tid] - musig[r][0]) * musig[r][1] + bt;
  }
}

// ---------------------------------------------------------------------------
extern "C" void kernel_launch(void* const* d_in, const int* in_sizes, int n_in,
                              void* d_out, int out_size, void* d_ws,
                              size_t ws_size, hipStream_t stream) {
  const float* inQ = (const float*)d_in[0];
  const float* inK = (const float*)d_in[1];
  const float* inV = (const float*)d_in[2];
  const void* mask = d_in[3];
  const float* matrix = (const float*)d_in[4];
  const float* Wq = (const float*)d_in[5];
  const float* Wk = (const float*)d_in[6];
  const float* Wv = (const float*)d_in[7];
  const float* Wv2 = (const float*)d_in[8];
  const float* Wfc = (const float*)d_in[9];
  const float* lng = (const float*)d_in[10];
  const float* lnb = (const float*)d_in[11];
  const float* fulng = (const float*)d_in[12];
  const float* fulnb = (const float*)d_in[13];
  const float* fuw1 = (const float*)d_in[14];
  const float* fub1 = (const float*)d_in[15];
  const float* fuw2 = (const float*)d_in[16];
  const float* fub2 = (const float*)d_in[17];

  float* ws = (float*)d_ws;
  __hip_bfloat16* Qb = (__hip_bfloat16*)(ws + OFF_QB);
  __hip_bfloat16* Kb = (__hip_bfloat16*)(ws + OFF_KB);
  __hip_bfloat16* Vt = (__hip_bfloat16*)(ws + OFF_VT);
  float* Vp2 = ws + OFF_VP2;
  __hip_bfloat16* ctxb = (__hip_bfloat16*)(ws + OFF_CTXB);
  __hip_bfloat16* ctx2b = (__hip_bfloat16*)(ws + OFF_CTX2B);
  __hip_bfloat16* gws = (__hip_bfloat16*)(ws + OFF_G);
  unsigned int* flag = (unsigned int*)(ws + OFF_FLAG);
  unsigned long long* pmask = (unsigned long long*)(ws + OFF_PM);

  float* out = (float*)d_out;
  float* mout = out + BB * SS * DM;

  // Mask pack: if in_sizes[3] says 4-byte elements (bytes semantics), int 0/1
  // and float 0/1.0 are both exactly (word != 0) -> flagless path, 2 fewer
  // dispatches. Any other value -> original runtime-flag path (byte masks,
  // element-count semantics).
  const long long MASKN = (long long)BB * NH * SS * SS;  // 33554432 elements
  if (in_sizes[3] == (int)(MASKN * 4)) {
    mask_pack4_kernel<<<4096, 256, 0, stream>>>((const unsigned int*)mask,
                                                pmask);
  } else {
    hipMemsetAsync(flag, 0, 4, stream);
    mask_or_kernel<<<64, 256, 0, stream>>>((const unsigned int*)mask, flag);
    mask_pack_kernel<<<4096, 256, 0, stream>>>(mask, pmask, flag);
  }
  gemm_qkv_vp2_kernel<<<2048, 256, 0, stream>>>(inQ, inK, inV, Wq, Wk, Wv, Wv2,
                                                Qb, Kb, Vt, Vp2);
  attn_kernel<<<512, 512, 0, stream>>>(Qb, Kb, Vt, pmask, matrix, fulng, fulnb,
                                       fuw1, fub1, fuw2, fub2, ctxb, gws);
  mout_ctx2_kernel<<<1536, 256, 0, stream>>>(matrix, gws, mout, Vp2, ctx2b);
  final_kernel<<<256, 256, 0, stream>>>(ctxb, ctx2b, Wfc, lng, lnb, out);
}

// Round 10
// 379.802 us; speedup vs baseline: 1.3001x; 1.0051x over previous
//
#include <hip/hip_runtime.h>
#include <hip/hip_bf16.h>

#define BB 16
#define SS 512
#define DM 256
#define NH 8

// workspace layout in float units
#define OFF_QB    0         // bf16 Q  [b,s,c]  2097152 elem
#define OFF_KB    1048576   // bf16 K  [b,s,c]
#define OFF_VT    2097152   // bf16 V^T [b,c,s]
#define OFF_VP2   3145728   // f32 [b,s,32]
#define OFF_CTXB  3407872   // bf16 ctx [b,s,256]
#define OFF_CTX2B 4456448   // bf16 ctx2 [b,s,32]
#define OFF_G     4587520   // bf16 g [b,q,k]
#define OFF_FLAG  6684672   // 1 uint
#define OFF_PM    6684674   // packed mask bits, 524288 u64 = 4 MB
// total ws = 7733250 floats ~= 29.5 MB

#define SCALE 0.17677669529663687f
// SCALE * log2(e): exp(SCALE*x) == exp2(KE2*x)
#define KE2 0.2550348623f

typedef __attribute__((ext_vector_type(8))) short bfrag8;  // 8 bf16 (4 VGPR)
typedef __attribute__((ext_vector_type(4))) float facc4;   // MFMA accumulator

// ---------------------------------------------------------------------------
// K0: OR-reduce first 64K words of the mask into *acc (fallback path only).
__global__ void mask_or_kernel(const unsigned int* __restrict__ w,
                               unsigned int* __restrict__ acc) {
  __shared__ unsigned int sh[256];
  unsigned int a = 0;
  int base = blockIdx.x * 1024;
  for (int i = threadIdx.x; i < 1024; i += 256) a |= w[base + i];
  sh[threadIdx.x] = a;
  __syncthreads();
  for (int s = 128; s > 0; s >>= 1) {
    if (threadIdx.x < s) sh[threadIdx.x] |= sh[threadIdx.x + s];
    __syncthreads();
  }
  if (threadIdx.x == 0) atomicOr(acc, sh[0]);
}

// ---------------------------------------------------------------------------
// K0b: flagged pack (fallback; handles byte/int/float via runtime flag).
__global__ __launch_bounds__(256) void mask_pack_kernel(
    const void* __restrict__ mask, unsigned long long* __restrict__ pm,
    const unsigned int* __restrict__ orv) {
  const unsigned int rawor = *orv;
  const int flagv = (rawor <= 1u) ? 0 : ((rawor == 0x3F800000u) ? 2 : 1);
  const int lane = threadIdx.x & 63;
  const int wv = threadIdx.x >> 6;
  const int w0 = (blockIdx.x * 4 + wv) * 32;
  const unsigned char* mb = (const unsigned char*)mask;
  const int* mi = (const int*)mask;
  const float* mf = (const float*)mask;
  unsigned long long myw = 0;
#pragma unroll 4
  for (int i = 0; i < 32; i++) {
    long long idx = (long long)(w0 + i) * 64 + lane;
    bool m;
    if (flagv == 1) m = (mb[idx] != 0);
    else if (flagv == 0) m = (mi[idx] != 0);
    else m = (mf[idx] != 0.f);
    unsigned long long bits = __ballot(m);
    if (lane == i) myw = bits;
  }
  if (lane < 32) pm[w0 + lane] = myw;
}

// ---------------------------------------------------------------------------
// K1: gemm_qkv + vp2 + mask_pack4 in ONE dispatch (R10). All three are
// mutually independent; merging lets pack's pure-BW blocks (134 MB mask read)
// co-resident with GEMM's compute blocks instead of running serially after.
// blocks 0..1535:    Q/K/V projection GEMM (body unchanged).
// blocks 1536..2047: Vp2 = inV @ Wv2 (body unchanged).
// blocks 2048..6143: flagless 4-byte mask pack (body unchanged; proven
//                    4-byte by R1 FETCH=134MB; int 0/1 and float 1.0 are
//                    both exactly word!=0).
__global__ __launch_bounds__(256) void proj_pack_kernel(
    const float* __restrict__ inQ, const float* __restrict__ inK,
    const float* __restrict__ inV,
    const float* __restrict__ Wq, const float* __restrict__ Wk,
    const float* __restrict__ Wv, const float* __restrict__ Wv2,
    __hip_bfloat16* __restrict__ Qb, __hip_bfloat16* __restrict__ Kb,
    __hip_bfloat16* __restrict__ Vt, float* __restrict__ Vp2,
    const unsigned int* __restrict__ mask4,
    unsigned long long* __restrict__ pm) {
  __shared__ __align__(16) char smem[16640];
  const int tid = threadIdx.x;

  if (blockIdx.x < 1536) {
    // ---- gemm_qkv body (unchanged) ----
    auto As = reinterpret_cast<__hip_bfloat16(*)[40]>(smem);          // 64x40
    auto Bs = reinterpret_cast<__hip_bfloat16(*)[40]>(smem + 5120);   // 64x40
    const int bid = blockIdx.x;
    const int matid = bid >> 9;
    const int mblk = (bid & 511) >> 2;
    const int nblk = bid & 3;
    const int m0 = mblk * 64;
    const int n0 = nblk * 64;
    const float* X = (matid == 0) ? inQ : (matid == 1) ? inK : inV;
    const float* W = (matid == 0) ? Wq : (matid == 1) ? Wk : Wv;

    const int lane = tid & 63;
    const int w = tid >> 6;
    const int wm = w & 1, wn = w >> 1;
    const int cl = lane & 15, quad = lane >> 4;
    const int arow = tid >> 2, ak8 = (tid & 3) * 8;
    const int bn = tid & 63, bk8 = (tid >> 6) * 8;

    facc4 acc[2][2];
#pragma unroll
    for (int t = 0; t < 2; t++)
#pragma unroll
      for (int u = 0; u < 2; u++) acc[t][u] = (facc4){0.f, 0.f, 0.f, 0.f};

#pragma unroll 1
    for (int kc = 0; kc < 8; kc++) {
      float4 x0 = *(const float4*)&X[(m0 + arow) * 256 + kc * 32 + ak8];
      float4 x1 = *(const float4*)&X[(m0 + arow) * 256 + kc * 32 + ak8 + 4];
      float wv[8];
#pragma unroll
      for (int j = 0; j < 8; j++)
        wv[j] = W[(kc * 32 + bk8 + j) * 256 + n0 + bn];
      __syncthreads();
      {
        __hip_bfloat16 ta[8];
        ta[0] = __float2bfloat16(x0.x); ta[1] = __float2bfloat16(x0.y);
        ta[2] = __float2bfloat16(x0.z); ta[3] = __float2bfloat16(x0.w);
        ta[4] = __float2bfloat16(x1.x); ta[5] = __float2bfloat16(x1.y);
        ta[6] = __float2bfloat16(x1.z); ta[7] = __float2bfloat16(x1.w);
        *(uint4*)&As[arow][ak8] = *(uint4*)ta;
        __hip_bfloat16 tb[8];
#pragma unroll
        for (int j = 0; j < 8; j++) tb[j] = __float2bfloat16(wv[j]);
        *(uint4*)&Bs[bn][bk8] = *(uint4*)tb;
      }
      __syncthreads();
      bfrag8 aA[2], bB[2];
#pragma unroll
      for (int t = 0; t < 2; t++)
        aA[t] = *(const bfrag8*)&As[wm * 32 + t * 16 + cl][quad * 8];
#pragma unroll
      for (int u = 0; u < 2; u++)
        bB[u] = *(const bfrag8*)&Bs[wn * 32 + u * 16 + cl][quad * 8];
#pragma unroll
      for (int t = 0; t < 2; t++)
#pragma unroll
        for (int u = 0; u < 2; u++)
          acc[t][u] = __builtin_amdgcn_mfma_f32_16x16x32_bf16(aA[t], bB[u],
                                                             acc[t][u], 0, 0, 0);
    }

    if (matid < 2) {
      __hip_bfloat16* Y = (matid == 0) ? Qb : Kb;
#pragma unroll
      for (int t = 0; t < 2; t++)
#pragma unroll
        for (int u = 0; u < 2; u++)
#pragma unroll
          for (int reg = 0; reg < 4; reg++)
            Y[(m0 + wm * 32 + t * 16 + quad * 4 + reg) * 256 + n0 + wn * 32 +
              u * 16 + cl] = __float2bfloat16(acc[t][u][reg]);
    } else {
#pragma unroll
      for (int t = 0; t < 2; t++)
#pragma unroll
        for (int u = 0; u < 2; u++) {
          int c = n0 + wn * 32 + u * 16 + cl;
          int mg = m0 + wm * 32 + t * 16 + quad * 4;
          int b = mg >> 9, s = mg & 511;
          __hip_bfloat16 pk[4];
#pragma unroll
          for (int reg = 0; reg < 4; reg++)
            pk[reg] = __float2bfloat16(acc[t][u][reg]);
          *(ushort4*)&Vt[(((b << 8) + c) << 9) + s] = *(ushort4*)pk;
        }
    }
  } else if (blockIdx.x < 2048) {
    // ---- vp2 body (unchanged) ----
    auto xs = reinterpret_cast<float(*)[260]>(smem);  // 16x260
    const int r0 = (blockIdx.x - 1536) * 16;
    for (int e = tid; e < 16 * 256; e += 256) {
      int r = e >> 8, i = e & 255;
      xs[r][i] = inV[(r0 + r) * 256 + i];
    }
    __syncthreads();
    const int c2 = tid & 31, rr = tid >> 5;
    float a0 = 0.f, a1 = 0.f;
    for (int i = 0; i < 256; i += 4) {
      float w0 = Wv2[i * 32 + c2], w1 = Wv2[(i + 1) * 32 + c2];
      float w2 = Wv2[(i + 2) * 32 + c2], w3 = Wv2[(i + 3) * 32 + c2];
      float4 xa = *(const float4*)&xs[rr][i];
      float4 xb = *(const float4*)&xs[rr + 8][i];
      a0 += xa.x * w0 + xa.y * w1 + xa.z * w2 + xa.w * w3;
      a1 += xb.x * w0 + xb.y * w1 + xb.z * w2 + xb.w * w3;
    }
    Vp2[(r0 + rr) * 32 + c2] = a0;
    Vp2[(r0 + rr + 8) * 32 + c2] = a1;
  } else {
    // ---- flagless 4-byte mask pack body (unchanged) ----
    const int lane = tid & 63;
    const int wv = tid >> 6;
    const int w0 = ((blockIdx.x - 2048) * 4 + wv) * 32;
    unsigned long long myw = 0;
#pragma unroll 4
    for (int i = 0; i < 32; i++) {
      unsigned int v = mask4[(long long)(w0 + i) * 64 + lane];
      unsigned long long bits = __ballot(v != 0u);
      if (lane == i) myw = bits;
    }
    if (lane < 32) pm[w0 + lane] = myw;
  }
}

// ---------------------------------------------------------------------------
// K2: fused attention — EXACT R2 champion config: 16 q-rows/block, 1 block/CU,
// full-S unnormalized-e LDS buffer; QK unroll 2, AV unroll 4, gate unroll 1.
// (R8 hoist/unroll spilled to scratch; R7 global-P blew HBM; R3 split doubled
// work — all reverted. This body is the verified local floor.)
__global__ __launch_bounds__(512, 2) void attn_kernel(
    const __hip_bfloat16* __restrict__ Qb, const __hip_bfloat16* __restrict__ Kb,
    const __hip_bfloat16* __restrict__ Vt,
    const unsigned long long* __restrict__ pm,
    const float* __restrict__ matrix,
    const float* __restrict__ fulng, const float* __restrict__ fulnb,
    const float* __restrict__ fuw1, const float* __restrict__ fub1,
    const float* __restrict__ fuw2, const float* __restrict__ fub2,
    __hip_bfloat16* __restrict__ ctxb, __hip_bfloat16* __restrict__ gws) {
  // 8*16*520*2 = 133120 B; row stride 1040 B (16B-aligned; 260 mod 32 = 4)
  __shared__ __align__(16) __hip_bfloat16 Sb[NH][16][520];
  __shared__ float inv_s[NH][16];
  __shared__ float gp[80];  // GW1[0..53], S1[54..59], C1[60..65], w2[66..71], b2[72]

  const int tid = threadIdx.x;
  const int lane = tid & 63;
  const int h = tid >> 6;
  const int cl = lane & 15, quad = lane >> 4;
  // XCD swizzle: 2 batches per XCD
  const int b = ((blockIdx.x & 7) << 1) | (blockIdx.x >> 8);
  const int q0 = ((blockIdx.x >> 3) & 31) * 16;

  // gate-param precompute (visible after the main __syncthreads below)
  if (tid < 6) {
    const int j = tid;
    float s1 = 0.f, c1 = fub1[j];
#pragma unroll
    for (int t = 0; t < 9; t++) {
      float w = fuw1[t * 6 + j];
      float gw = fulng[t] * w;
      gp[t * 6 + j] = gw;
      s1 += gw;
      c1 += fulnb[t] * w;
    }
    gp[54 + j] = s1;
    gp[60 + j] = c1;
    gp[66 + j] = fuw2[j];
    if (j == 0) gp[72] = fub2[0];
  }

  // packed-mask base for this (b, h, q0); row r word w at pmb[r*8 + w]
  const unsigned long long* pmb = pm + (((b * NH + h) << 9) + q0) * 8;

  const bfrag8 aQ =
      *(const bfrag8*)&Qb[(((b << 9) + q0 + cl) << 8) + h * 32 + quad * 8];
  const __hip_bfloat16* KbB = &Kb[((b << 9) << 8) + h * 32 + quad * 8];
  const __hip_bfloat16* VtB = &Vt[(((b << 8) + h * 32) << 9)];

  // ---- single pass: scores -> e -> LDS, accumulate row sums ----
  float l[4] = {0.f, 0.f, 0.f, 0.f};
#pragma unroll 2
  for (int w8 = 0; w8 < 8; w8++) {
    unsigned long long mw[4];
#pragma unroll
    for (int r = 0; r < 4; r++)
      mw[r] = pmb[(quad * 4 + r) * 8 + w8] >> cl;  // bit n4*16: col n4*16+cl
#pragma unroll
    for (int n4 = 0; n4 < 4; n4++) {
      const int nt = w8 * 4 + n4;
      bfrag8 bK = *(const bfrag8*)&KbB[(nt * 16 + cl) << 8];
      facc4 cc = {0.f, 0.f, 0.f, 0.f};
      cc = __builtin_amdgcn_mfma_f32_16x16x32_bf16(aQ, bK, cc, 0, 0, 0);
#pragma unroll
      for (int r = 0; r < 4; r++) {
        float e = ((mw[r] >> (n4 * 16)) & 1ULL) ? 0.f : exp2f(KE2 * cc[r]);
        l[r] += e;
        Sb[h][quad * 4 + r][nt * 16 + cl] = __float2bfloat16(e);
      }
    }
  }
#pragma unroll
  for (int r = 0; r < 4; r++)
#pragma unroll
    for (int off = 1; off <= 8; off <<= 1) l[r] += __shfl_xor(l[r], off);
  float invl[4];
#pragma unroll
  for (int r = 0; r < 4; r++) invl[r] = 1.f / l[r];
  if (cl == 0) {
#pragma unroll
    for (int r = 0; r < 4; r++) inv_s[h][quad * 4 + r] = invl[r];
  }
  __syncthreads();  // e of all heads + inv_s + gp visible

  // ---- AV: ctx = (sum e*V) * invl (normalization deferred to epilogue) ----
  facc4 a0 = {0.f, 0.f, 0.f, 0.f}, a1 = {0.f, 0.f, 0.f, 0.f};
#pragma unroll 4
  for (int ks = 0; ks < 16; ks++) {
    bfrag8 aP = *(const bfrag8*)&Sb[h][cl][ks * 32 + quad * 8];
    bfrag8 b0 = *(const bfrag8*)&VtB[(cl << 9) + ks * 32 + quad * 8];
    bfrag8 b1 = *(const bfrag8*)&VtB[((16 + cl) << 9) + ks * 32 + quad * 8];
    a0 = __builtin_amdgcn_mfma_f32_16x16x32_bf16(aP, b0, a0, 0, 0, 0);
    a1 = __builtin_amdgcn_mfma_f32_16x16x32_bf16(aP, b1, a1, 0, 0, 0);
  }

  // ---- gate: thread -> (gq, 4 consecutive k), 4 strips of 128 cols ----
  {
    const int gq = tid >> 5;
    const int g32 = (tid & 31) * 4;
#pragma unroll 1
    for (int s = 0; s < 4; s++) {
      const int k4 = s * 128 + g32;
      float4 mrow =
          *(const float4*)&matrix[((b << 9) + q0 + gq) * 512 + k4];
      float p[NH][4];
#pragma unroll
      for (int hh = 0; hh < NH; hh++) {
        const float iv = inv_s[hh][gq];
        ushort4 sv = *(const ushort4*)&Sb[hh][gq][k4];
        p[hh][0] = __bfloat162float(*(__hip_bfloat16*)&sv.x) * iv;
        p[hh][1] = __bfloat162float(*(__hip_bfloat16*)&sv.y) * iv;
        p[hh][2] = __bfloat162float(*(__hip_bfloat16*)&sv.z) * iv;
        p[hh][3] = __bfloat162float(*(__hip_bfloat16*)&sv.w) * iv;
      }
      const float mcomp[4] = {mrow.x, mrow.y, mrow.z, mrow.w};
      __hip_bfloat16 gout[4];
#pragma unroll
      for (int i = 0; i < 4; i++) {
        float v[9];
        v[0] = mcomp[i];
#pragma unroll
        for (int t = 0; t < NH; t++) v[1 + t] = p[t][i];
        float s1 = 0.f, s2 = 0.f;
#pragma unroll
        for (int t = 0; t < 9; t++) {
          s1 += v[t];
          s2 += v[t] * v[t];
        }
        float mu = s1 * (1.f / 9.f);
        float var = s2 * (1.f / 9.f) - mu * mu;
        float inv = rsqrtf(var + 1e-5f);
        float o = gp[72];
#pragma unroll
        for (int j = 0; j < 6; j++) {
          float d = 0.f;
#pragma unroll
          for (int t = 0; t < 9; t++) d += v[t] * gp[t * 6 + j];
          float z = inv * (d - mu * gp[54 + j]) + gp[60 + j];
          z = fmaxf(z, 0.f);
          o += z * gp[66 + j];
        }
        gout[i] = __float2bfloat16(1.f / (1.f + __expf(-o)));
      }
      *(ushort4*)&gws[((b << 9) + q0 + gq) * 512 + k4] = *(ushort4*)gout;
    }
  }

  // ---- epilogue: scale + write ctx ----
#pragma unroll
  for (int r = 0; r < 4; r++) {
    int row = quad * 4 + r;
    ctxb[((b << 9) + q0 + row) * 256 + h * 32 + cl] =
        __float2bfloat16(a0[r] * invl[r]);
    ctxb[((b << 9) + q0 + row) * 256 + h * 32 + 16 + cl] =
        __float2bfloat16(a1[r] * invl[r]);
  }
}

// ---------------------------------------------------------------------------
// K3: mout + ctx2 concatenated (one dispatch, bodies unchanged).
__global__ __launch_bounds__(256) void mout_ctx2_kernel(
    const float* __restrict__ matrix, const __hip_bfloat16* __restrict__ g,
    float* __restrict__ mout, const float* __restrict__ Vp2,
    __hip_bfloat16* __restrict__ ctx2b) {
  __shared__ __align__(16) char smem[25088];
  const int tid = threadIdx.x;

  if (blockIdx.x < 1024) {
    // ---- mout body (unchanged) ----
    auto Gs = reinterpret_cast<float(*)[65]>(smem);  // 64x65
    const int b = blockIdx.x >> 6;
    const int j0 = ((blockIdx.x >> 3) & 7) * 64;
    const int i0 = (blockIdx.x & 7) * 64;

    {
      int r = tid >> 2, c0 = (tid & 3) * 16;
      const __hip_bfloat16* gpx = g + (((b << 9) + i0 + r) << 9) + j0 + c0;
      ushort us[16];
      *(uint4*)(us) = *(const uint4*)(gpx);
      *(uint4*)(us + 8) = *(const uint4*)(gpx + 8);
#pragma unroll
      for (int k = 0; k < 16; k++) {
        __hip_bfloat16 hv = *(__hip_bfloat16*)&us[k];
        Gs[r][c0 + k] = __bfloat162float(hv);
      }
    }
    __syncthreads();

    {
      int jj = tid >> 2, ic = (tid & 3) * 16;
      const float* mp = matrix + (((b << 9) + j0 + jj) << 9) + i0 + ic;
      float* op = mout + (((b << 9) + j0 + jj) << 9) + i0 + ic;
#pragma unroll
      for (int v4 = 0; v4 < 4; v4++) {
        float4 m = *(const float4*)(mp + v4 * 4);
        float4 o;
        o.x = m.x * Gs[ic + v4 * 4 + 0][jj];
        o.y = m.y * Gs[ic + v4 * 4 + 1][jj];
        o.z = m.z * Gs[ic + v4 * 4 + 2][jj];
        o.w = m.w * Gs[ic + v4 * 4 + 3][jj];
        *(float4*)(op + v4 * 4) = o;
      }
    }
  } else {
    // ---- ctx2 body (unchanged) ----
    auto Ms = reinterpret_cast<float(*)[128]>(smem);            // 16x128
    auto Vs2t = reinterpret_cast<float(*)[132]>(smem + 8192);   // 32x132
    const int cid = blockIdx.x - 1024;
    const int b = cid >> 5;
    const int s0 = (cid & 31) * 16;
    const int dv = tid & 31, rg = tid >> 5;
    float acc0 = 0.f, acc1 = 0.f;
    for (int kc = 0; kc < 4; kc++) {
      __syncthreads();
#pragma unroll
      for (int it = 0; it < 8; it++) {
        int idx = tid + it * 256;
        int r = idx >> 7, cc = idx & 127;
        Ms[r][cc] = matrix[((b << 9) + s0 + r) * 512 + kc * 128 + cc];
      }
#pragma unroll
      for (int it = 0; it < 16; it++) {
        int e = tid + it * 256;
        int k = e >> 5, dv2 = e & 31;
        Vs2t[dv2][k] = Vp2[((b << 9) + kc * 128 + k) * 32 + dv2];
      }
      __syncthreads();
      for (int k = 0; k < 128; k += 4) {
        float4 vv = *(const float4*)&Vs2t[dv][k];
        float4 m0 = *(const float4*)&Ms[rg][k];
        float4 m1 = *(const float4*)&Ms[rg + 8][k];
        acc0 += m0.x * vv.x + m0.y * vv.y + m0.z * vv.z + m0.w * vv.w;
        acc1 += m1.x * vv.x + m1.y * vv.y + m1.z * vv.z + m1.w * vv.w;
      }
    }
    ctx2b[((b << 9) + s0 + rg) * 32 + dv] = __float2bfloat16(acc0);
    ctx2b[((b << 9) + s0 + rg + 8) * 32 + dv] = __float2bfloat16(acc1);
  }
}

// ---------------------------------------------------------------------------
// K5: out = LN([ctxb|ctx2b] @ Wfc) (unchanged).
__global__ __launch_bounds__(256) void final_kernel(
    const __hip_bfloat16* __restrict__ ctxb,
    const __hip_bfloat16* __restrict__ ctx2b, const float* __restrict__ Wfc,
    const float* __restrict__ lng, const float* __restrict__ lnb,
    float* __restrict__ out) {
  __shared__ __align__(16) __hip_bfloat16 As[32][40];
  __shared__ __align__(16) __hip_bfloat16 Bs[256][40];
  __shared__ __align__(16) float xs[32][260];
  __shared__ float red2[32][8][2];
  __shared__ float musig[32][2];
  const int tid = threadIdx.x;
  const int m0 = blockIdx.x * 32;
  const int lane = tid & 63, w = tid >> 6;
  const int cl = lane & 15, quad = lane >> 4;
  const int arow = tid >> 3, ak4 = (tid & 7) * 4;

  facc4 acc[2][4];
#pragma unroll
  for (int t = 0; t < 2; t++)
#pragma unroll
    for (int u = 0; u < 4; u++) acc[t][u] = (facc4){0.f, 0.f, 0.f, 0.f};

#pragma unroll 1
  for (int kc = 0; kc < 9; kc++) {
    ushort4 av;
    if (kc < 8)
      av = *(const ushort4*)&ctxb[(m0 + arow) * 256 + kc * 32 + ak4];
    else
      av = *(const ushort4*)&ctx2b[(m0 + arow) * 32 + ak4];
    float wv[32];
#pragma unroll
    for (int j = 0; j < 32; j++) wv[j] = Wfc[(kc * 32 + j) * 256 + tid];
    __syncthreads();
    *(ushort4*)&As[arow][ak4] = av;
    {
      __hip_bfloat16 tw[32];
#pragma unroll
      for (int j = 0; j < 32; j++) tw[j] = __float2bfloat16(wv[j]);
#pragma unroll
      for (int g = 0; g < 4; g++) *(uint4*)&Bs[tid][g * 8] = *(uint4*)&tw[g * 8];
    }
    __syncthreads();
    bfrag8 aA[2], bB[4];
#pragma unroll
    for (int t = 0; t < 2; t++)
      aA[t] = *(const bfrag8*)&As[t * 16 + cl][quad * 8];
#pragma unroll
    for (int u = 0; u < 4; u++)
      bB[u] = *(const bfrag8*)&Bs[w * 64 + u * 16 + cl][quad * 8];
#pragma unroll
    for (int t = 0; t < 2; t++)
#pragma unroll
      for (int u = 0; u < 4; u++)
        acc[t][u] =
            __builtin_amdgcn_mfma_f32_16x16x32_bf16(aA[t], bB[u], acc[t][u], 0, 0, 0);
  }

#pragma unroll
  for (int t = 0; t < 2; t++)
#pragma unroll
    for (int u = 0; u < 4; u++)
#pragma unroll
      for (int reg = 0; reg < 4; reg++)
        xs[t * 16 + quad * 4 + reg][w * 64 + u * 16 + cl] = acc[t][u][reg];
  __syncthreads();

  {
    int r = tid >> 3, c0 = (tid & 7) * 32;
    float s1 = 0.f, s2 = 0.f;
    for (int j = 0; j < 32; j += 4) {
      float4 v = *(const float4*)&xs[r][c0 + j];
      s1 += v.x + v.y + v.z + v.w;
      s2 += v.x * v.x + v.y * v.y + v.z * v.z + v.w * v.w;
    }
    red2[r][tid & 7][0] = s1;
    red2[r][tid & 7][1] = s2;
  }
  __syncthreads();
  if (tid < 32) {
    float s1 = 0.f, s2 = 0.f;
#pragma unroll
    for (int j = 0; j < 8; j++) {
      s1 += red2[tid][j][0];
      s2 += red2[tid][j][1];
    }
    float mu = s1 * (1.f / 256.f);
    float var = s2 * (1.f / 256.f) - mu * mu;
    musig[tid][0] = mu;
    musig[tid][1] = rsqrtf(var + 1e-5f);
  }
  __syncthreads();
  {
    float gt = lng[tid], bt = lnb[tid];
#pragma unroll 4
    for (int r = 0; r < 32; r++)
      out[(m0 + r) * 256 + tid] =
          gt * (xs[r][tid] - musig[r][0]) * musig[r][1] + bt;
  }
}

// ---------------------------------------------------------------------------
extern "C" void kernel_launch(void* const* d_in, const int* in_sizes, int n_in,
                              void* d_out, int out_size, void* d_ws,
                              size_t ws_size, hipStream_t stream) {
  const float* inQ = (const float*)d_in[0];
  const float* inK = (const float*)d_in[1];
  const float* inV = (const float*)d_in[2];
  const void* mask = d_in[3];
  const float* matrix = (const float*)d_in[4];
  const float* Wq = (const float*)d_in[5];
  const float* Wk = (const float*)d_in[6];
  const float* Wv = (const float*)d_in[7];
  const float* Wv2 = (const float*)d_in[8];
  const float* Wfc = (const float*)d_in[9];
  const float* lng = (const float*)d_in[10];
  const float* lnb = (const float*)d_in[11];
  const float* fulng = (const float*)d_in[12];
  const float* fulnb = (const float*)d_in[13];
  const float* fuw1 = (const float*)d_in[14];
  const float* fub1 = (const float*)d_in[15];
  const float* fuw2 = (const float*)d_in[16];
  const float* fub2 = (const float*)d_in[17];

  float* ws = (float*)d_ws;
  __hip_bfloat16* Qb = (__hip_bfloat16*)(ws + OFF_QB);
  __hip_bfloat16* Kb = (__hip_bfloat16*)(ws + OFF_KB);
  __hip_bfloat16* Vt = (__hip_bfloat16*)(ws + OFF_VT);
  float* Vp2 = ws + OFF_VP2;
  __hip_bfloat16* ctxb = (__hip_bfloat16*)(ws + OFF_CTXB);
  __hip_bfloat16* ctx2b = (__hip_bfloat16*)(ws + OFF_CTX2B);
  __hip_bfloat16* gws = (__hip_bfloat16*)(ws + OFF_G);
  unsigned int* flag = (unsigned int*)(ws + OFF_FLAG);
  unsigned long long* pmask = (unsigned long long*)(ws + OFF_PM);

  float* out = (float*)d_out;
  float* mout = out + BB * SS * DM;

  const long long MASKN = (long long)BB * NH * SS * SS;  // 33554432 elements
  if (in_sizes[3] == (int)(MASKN * 4)) {
    // Fast path: 4-byte mask -> pack fused into the projection dispatch
    // (independent work, co-resident blocks overlap BW with compute).
    proj_pack_kernel<<<6144, 256, 0, stream>>>(
        inQ, inK, inV, Wq, Wk, Wv, Wv2, Qb, Kb, Vt, Vp2,
        (const unsigned int*)mask, pmask);
  } else {
    // Fallback: flagged serial chain (byte masks / element-count semantics).
    hipMemsetAsync(flag, 0, 4, stream);
    mask_or_kernel<<<64, 256, 0, stream>>>((const unsigned int*)mask, flag);
    mask_pack_kernel<<<4096, 256, 0, stream>>>(mask, pmask, flag);
    proj_pack_kernel<<<2048, 256, 0, stream>>>(
        inQ, inK, inV, Wq, Wk, Wv, Wv2, Qb, Kb, Vt, Vp2,
        (const unsigned int*)mask, pmask);  // blocks <2048: proj only
  }
  attn_kernel<<<512, 512, 0, stream>>>(Qb, Kb, Vt, pmask, matrix, fulng, fulnb,
                                       fuw1, fub1, fuw2, fub2, ctxb, gws);
  mout_ctx2_kernel<<<1536, 256, 0, stream>>>(matrix, gws, mout, Vp2, ctx2b);
  final_kernel<<<256, 256, 0, stream>>>(ctxb, ctx2b, Wfc, lng, lnb, out);
}